// Round 2
// baseline (646.394 us; speedup 1.0000x reference)
//
#include <hip/hip_runtime.h>
#include <hip/hip_bf16.h>

#define HW    1600
#define NB    2
#define NHEAD 8
#define HD    32
#define WS2   225
#define WDIM  40
#define CDIM  256
#define PROJ  819200   // NB*NHEAD*HW*HD
#define TSC   5.656854249492381f   // sqrt(32)

static __device__ __forceinline__ float b2f(__hip_bfloat16 x) { return __bfloat162float(x); }

// load element i of a float-ish input buffer whose dtype is decided by f32
static __device__ __forceinline__ float ldf(const void* p, size_t i, bool f32) {
    return f32 ? ((const float*)p)[i] : b2f(((const __hip_bfloat16*)p)[i]);
}
static __device__ __forceinline__ void st_out(void* p, size_t i, float v, bool f32) {
    if (f32) ((float*)p)[i] = v;
    else     ((__hip_bfloat16*)p)[i] = __float2bfloat16(v);
}

// ---------------- Kernel 0: input dtype detection ----------------
// If inputs are fp32 but read as bf16, low half-words decode to garbage with
// huge magnitude / NaN with ~40% probability per element -> certain over 4096.
// If inputs are bf16 (N(0,1) data), every |x| < 10.
__global__ __launch_bounds__(64) void detect_kernel(const void* qv, int* flag) {
    const __hip_bfloat16* qb = (const __hip_bfloat16*)qv;
    int bad = 0;
    for (int i = threadIdx.x; i < 4096; i += 64) {
        float v = b2f(qb[i]);
        if (!(v > -1e6f && v < 1e6f)) bad = 1;   // catches NaN too
    }
    bad = (__any(bad) ? 1 : 0);
    if (threadIdx.x == 0) *flag = bad;
}

// ---------------- Kernel 1: projections (q,k,v) ----------------
// grid (25, 256, 6), block 64. z = t*2 + n. Thread = one (t,n,o,p).
// qs/ks/vs layout: [n, nh, p, d] bf16 (position-major per head). qs pre-scaled by 1/T.
__global__ __launch_bounds__(64) void proj_kernel(
    const void* __restrict__ q, const void* __restrict__ k, const void* __restrict__ v,
    const void* __restrict__ Wq, const void* __restrict__ bq,
    const void* __restrict__ Wk, const void* __restrict__ bk,
    const void* __restrict__ Wv, const void* __restrict__ bv,
    const int* __restrict__ flag,
    __hip_bfloat16* __restrict__ qs, __hip_bfloat16* __restrict__ ks,
    __hip_bfloat16* __restrict__ vs)
{
    const int p = blockIdx.x * 64 + threadIdx.x;
    const int o = blockIdx.y;
    const int z = blockIdx.z;
    const int t = z >> 1, n = z & 1;

    const void *x, *W, *b;
    __hip_bfloat16* dst; float scale;
    if (t == 0)      { x = q; W = Wq; b = bq; dst = qs; scale = 0.17677669529663687f; }
    else if (t == 1) { x = k; W = Wk; b = bk; dst = ks; scale = 1.0f; }
    else             { x = v; W = Wv; b = bv; dst = vs; scale = 1.0f; }

    const bool f32 = (*flag != 0);
    const size_t xoff = (size_t)n * CDIM * HW + p;
    const size_t woff = (size_t)o * CDIM;

    float acc = ldf(b, o, f32);
    if (f32) {
        const float* xr = (const float*)x + xoff;
        const float* Wr = (const float*)W + woff;
        #pragma unroll 8
        for (int c = 0; c < CDIM; ++c) acc += Wr[c] * xr[(size_t)c * HW];
    } else {
        const __hip_bfloat16* xr = (const __hip_bfloat16*)x + xoff;
        const __hip_bfloat16* Wr = (const __hip_bfloat16*)W + woff;
        #pragma unroll 8
        for (int c = 0; c < CDIM; ++c) acc += b2f(Wr[c]) * b2f(xr[(size_t)c * HW]);
    }
    acc *= scale;

    const int h = o >> 5, d = o & 31;
    dst[(((size_t)(n * NHEAD + h) * HW + p) * HD) + d] = __float2bfloat16(acc);
}

// ---------------- Kernel 2: fused local attention ----------------
// One wave per query (n,h,i). Block 256 = 4 waves. grid 6400.
__global__ __launch_bounds__(256) void attn_kernel(
    const __hip_bfloat16* __restrict__ qs, const __hip_bfloat16* __restrict__ ks,
    const __hip_bfloat16* __restrict__ vs,
    const void* __restrict__ rkw,   // [NH, WS2, HD]
    const void* __restrict__ rkb,   // [NH, WS2]
    const void* __restrict__ relv,  // [NH, HD, WS2]
    const int* __restrict__ flag,
    __hip_bfloat16* __restrict__ agg,   // [hw, n, 256] bf16 (ws)
    void* __restrict__ dout)            // element-indexed output buffer
{
    __shared__ float lds_q[4][HD];
    __shared__ float lds_a[4][WS2 + 7];

    const bool f32 = (*flag != 0);
    const int wave = threadIdx.x >> 6;
    const int lane = threadIdx.x & 63;
    const int qidx = blockIdx.x * 4 + wave;      // ((n*NH + h)*HW + i)
    const int i   = qidx % HW;
    const int nh_ = qidx / HW;
    const int h   = nh_ & (NHEAD - 1);
    const int y   = i / WDIM, xq = i % WDIM;

    if (lane < HD) lds_q[wave][lane] = b2f(qs[(size_t)qidx * HD + lane]);
    __syncthreads();

    const __hip_bfloat16* kbase = ks + (size_t)nh_ * HW * HD;

    float lg[4];
    float m = -1e30f;
    #pragma unroll
    for (int r = 0; r < 4; ++r) {
        const int w_ = lane + r * 64;
        float logit = -1e30f;
        if (w_ < WS2) {
            const int dy = w_ / 15 - 7, dx = w_ % 15 - 7;
            const int ky = y + dy, kx = xq + dx;
            // rel term: T * dot(qs, rkw) + rkb (qs holds q/T; ref uses unscaled q for rel)
            float rr = 0.f;
            const size_t rwo = ((size_t)h * WS2 + w_) * HD;
            if (f32) {
                const float* rw = (const float*)rkw + rwo;
                #pragma unroll
                for (int d = 0; d < HD; ++d) rr += lds_q[wave][d] * rw[d];
            } else {
                const __hip_bfloat16* rw = (const __hip_bfloat16*)rkw + rwo;
                #pragma unroll
                for (int d = 0; d < HD; ++d) rr += lds_q[wave][d] * b2f(rw[d]);
            }
            rr = rr * TSC + ldf(rkb, (size_t)h * WS2 + w_, f32);
            if ((unsigned)ky < WDIM && (unsigned)kx < WDIM) {
                const __hip_bfloat16* kr = kbase + (size_t)(ky * WDIM + kx) * HD;
                float qk = 0.f;
                #pragma unroll
                for (int d = 0; d < HD; ++d) qk += lds_q[wave][d] * b2f(kr[d]);
                logit = qk + rr;
            }
            if (!(logit == logit)) logit = -1e30f;   // NaN scrub (insurance)
        }
        lg[r] = logit;
        m = fmaxf(m, logit);
    }
    #pragma unroll
    for (int off = 32; off > 0; off >>= 1) m = fmaxf(m, __shfl_xor(m, off));
    float s = 0.f;
    #pragma unroll
    for (int r = 0; r < 4; ++r) { lg[r] = expf(lg[r] - m); s += lg[r]; }
    #pragma unroll
    for (int off = 32; off > 0; off >>= 1) s += __shfl_xor(s, off);
    const float inv = (s > 0.f) ? (1.0f / s) : 0.f;
    #pragma unroll
    for (int r = 0; r < 4; ++r) {
        const int w_ = lane + r * 64;
        if (w_ < WS2) {
            const float a = lg[r] * inv;
            lds_a[wave][w_] = a;
            st_out(dout, (size_t)PROJ + (size_t)qidx * WS2 + w_, a, f32);
        }
    }
    __syncthreads();

    if (lane < HD) {
        const int d = lane;
        const __hip_bfloat16* vbase = vs + (size_t)nh_ * HW * HD + d;
        float acc = 0.f;
        const size_t rvo = (size_t)(h * HD + d) * WS2;
        for (int w_ = 0; w_ < WS2; ++w_) {
            const int dy = w_ / 15 - 7, dx = w_ % 15 - 7;
            const int ky = y + dy, kx = xq + dx;
            if ((unsigned)ky < WDIM && (unsigned)kx < WDIM) {
                const float a = lds_a[wave][w_];
                acc += a * b2f(vbase[(size_t)(ky * WDIM + kx) * HD]);
                acc += a * ldf(relv, rvo + w_, f32);
            }
        }
        const int n = nh_ >> 3;
        agg[((size_t)i * NB + n) * CDIM + h * HD + d] = __float2bfloat16(acc);
    }
}

// ---------------- Kernel 3: output projection ----------------
__global__ __launch_bounds__(256) void out_kernel(
    const __hip_bfloat16* __restrict__ agg,
    const void* __restrict__ Wp, const void* __restrict__ bp,
    const int* __restrict__ flag,
    void* __restrict__ dout)
{
    __shared__ float row[CDIM];
    const bool f32 = (*flag != 0);
    const int rb = blockIdx.x;                 // i*2 + n
    row[threadIdx.x] = b2f(agg[(size_t)rb * CDIM + threadIdx.x]);
    __syncthreads();
    const int o = threadIdx.x;
    float acc = ldf(bp, o, f32);
    if (f32) {
        const float* wr = (const float*)Wp + (size_t)o * CDIM;
        #pragma unroll 8
        for (int c = 0; c < CDIM; ++c) acc += row[c] * wr[c];
    } else {
        const __hip_bfloat16* wr = (const __hip_bfloat16*)Wp + (size_t)o * CDIM;
        #pragma unroll 8
        for (int c = 0; c < CDIM; ++c) acc += row[c] * b2f(wr[c]);
    }
    st_out(dout, (size_t)rb * CDIM + o, acc, f32);
}

extern "C" void kernel_launch(void* const* d_in, const int* in_sizes, int n_in,
                              void* d_out, int out_size, void* d_ws, size_t ws_size,
                              hipStream_t stream)
{
    const void* q   = d_in[0];
    const void* k   = d_in[1];
    const void* v   = d_in[2];
    const void* Wq  = d_in[3];
    const void* bq  = d_in[4];
    const void* Wk  = d_in[5];
    const void* bk  = d_in[6];
    const void* Wv  = d_in[7];
    const void* bv  = d_in[8];
    const void* rkw = d_in[9];
    const void* rkb = d_in[10];
    const void* rlv = d_in[11];
    const void* Wp  = d_in[12];
    const void* bp  = d_in[13];

    // workspace layout (6.55 MB total): flag | qs | ks | vs | agg  (all bf16 but flag)
    char* wsb = (char*)d_ws;
    int* flag = (int*)wsb;
    __hip_bfloat16* qs  = (__hip_bfloat16*)(wsb + 64);
    __hip_bfloat16* ks  = qs + PROJ;
    __hip_bfloat16* vs  = ks + PROJ;
    __hip_bfloat16* agg = vs + PROJ;

    detect_kernel<<<1, 64, 0, stream>>>(q, flag);
    proj_kernel<<<dim3(25, 256, 6), 64, 0, stream>>>(q, k, v, Wq, bq, Wk, bk, Wv, bv,
                                                     flag, qs, ks, vs);
    attn_kernel<<<dim3(6400), 256, 0, stream>>>(qs, ks, vs, rkw, rkb, rlv, flag, agg, d_out);
    out_kernel<<<dim3(3200), 256, 0, stream>>>(agg, Wp, bp, flag, d_out);
}

// Round 3
// 258.124 us; speedup vs baseline: 2.5042x; 2.5042x over previous
//
#include <hip/hip_runtime.h>
#include <hip/hip_bf16.h>

#define HW    1600
#define NB    2
#define NHEAD 8
#define HD    32
#define WS2   225
#define WDIM  40
#define CDIM  256
#define PROJ  819200                 // NB*NHEAD*HW*HD == NB*HW*CDIM/... (elements)
#define TSC   5.656854249492381f     // sqrt(32)

typedef __attribute__((ext_vector_type(8))) short short8;
typedef __attribute__((ext_vector_type(4))) float floatx4;

static __device__ __forceinline__ float bu2f(short u) {
    return __uint_as_float(((unsigned)(unsigned short)u) << 16);
}
static __device__ __forceinline__ short f2bu(float f) {
    __hip_bfloat16 h = __float2bfloat16(f);
    short s; __builtin_memcpy(&s, &h, 2); return s;
}
static __device__ __forceinline__ float ldf(const void* p, size_t i, bool f32) {
    return f32 ? ((const float*)p)[i] : __bfloat162float(((const __hip_bfloat16*)p)[i]);
}
static __device__ __forceinline__ void st_out(void* p, size_t i, float v, bool f32) {
    if (f32) ((float*)p)[i] = v;
    else     ((__hip_bfloat16*)p)[i] = __float2bfloat16(v);
}
// 8 contiguous elems as a bf16 MFMA fragment (converting if input is fp32)
static __device__ __forceinline__ short8 ld8bf(const void* p, size_t i, bool f32) {
    if (!f32) return *(const short8*)((const __hip_bfloat16*)p + i);
    const float* f = (const float*)p + i;
    short8 r;
    #pragma unroll
    for (int t = 0; t < 8; ++t) r[t] = f2bu(f[t]);
    return r;
}
// 8 contiguous elems as floats
static __device__ __forceinline__ void ld8f(const void* p, size_t i, bool f32, float* o) {
    if (f32) {
        const float* f = (const float*)p + i;
        #pragma unroll
        for (int t = 0; t < 8; ++t) o[t] = f[t];
    } else {
        short8 s = *(const short8*)((const __hip_bfloat16*)p + i);
        #pragma unroll
        for (int t = 0; t < 8; ++t) o[t] = bu2f(s[t]);
    }
}

// ---------------- Kernel 0: input dtype detection ----------------
__global__ __launch_bounds__(64) void detect_kernel(const void* qv, int* flag) {
    const __hip_bfloat16* qb = (const __hip_bfloat16*)qv;
    int bad = 0;
    for (int i = threadIdx.x; i < 4096; i += 64) {
        float v = __bfloat162float(qb[i]);
        if (!(v > -1e6f && v < 1e6f)) bad = 1;
    }
    bad = (__any(bad) ? 1 : 0);
    if (threadIdx.x == 0) *flag = bad;
}

// ---------------- Kernel 1: transpose x [n,256,1600] -> Xt [n,1600,256] bf16 ----------
__global__ __launch_bounds__(256) void tx_kernel(const void* __restrict__ x,
                                                 const int* __restrict__ flag,
                                                 __hip_bfloat16* __restrict__ Xt)
{
    __shared__ float tile[32][33];
    const bool f32 = (*flag != 0);
    const int p0 = blockIdx.x * 32, c0 = blockIdx.y * 32, n = blockIdx.z;
    const int tx = threadIdx.x & 31, ty = threadIdx.x >> 5;   // ty 0..7
    const size_t base = (size_t)n * CDIM * HW;
    #pragma unroll
    for (int s = 0; s < 4; ++s) {
        const int c = c0 + ty + 8 * s;
        tile[ty + 8 * s][tx] = ldf(x, base + (size_t)c * HW + p0 + tx, f32);
    }
    __syncthreads();
    #pragma unroll
    for (int s = 0; s < 4; ++s) {
        const int p = p0 + ty + 8 * s;
        Xt[base + (size_t)p * CDIM + c0 + tx] = __float2bfloat16(tile[tx][ty + 8 * s]);
    }
}

// ---------------- Kernel 2: projection GEMM via MFMA ----------------
// qs/ks/vs[p][o] = sum_c Xt[p][c] * W[o][c] + b[o]  (then *scale), stored [n,h,p,d] bf16.
// A = Xt rows (K-contig), B = W rows (K-contig). D: col=lane&15 (o), row=quad*4+reg (p).
__global__ __launch_bounds__(256) void proj_mfma(
    const __hip_bfloat16* __restrict__ Xt, const void* __restrict__ W,
    const void* __restrict__ bias, const int* __restrict__ flag,
    __hip_bfloat16* __restrict__ dst, float scale)
{
    const bool f32 = (*flag != 0);
    const int wave = threadIdx.x >> 6, lane = threadIdx.x & 63;
    const int tile = blockIdx.x * 4 + wave;          // 3200 tiles = 2n * 100p * 16o
    const int n = tile / 1600;
    const int r = tile - n * 1600;
    const int p0 = r & ~15;                          // (r/16)*16
    const int o0 = (r & 15) << 4;
    const int m = lane & 15, q = lane >> 4;

    const __hip_bfloat16* arow = Xt + (size_t)n * (HW * CDIM) + (size_t)(p0 + m) * CDIM + q * 8;
    const size_t bidx = (size_t)(o0 + m) * CDIM + q * 8;

    floatx4 acc = {0.f, 0.f, 0.f, 0.f};
    #pragma unroll
    for (int k = 0; k < 8; ++k) {
        short8 a = *(const short8*)(arow + k * 32);
        short8 b = ld8bf(W, bidx + k * 32, f32);
        acc = __builtin_amdgcn_mfma_f32_16x16x32_bf16(a, b, acc, 0, 0, 0);
    }
    const int col = lane & 15, row4 = (lane >> 4) * 4;
    const int o = o0 + col, h = o >> 5, d = o & 31;
    const float bv = ldf(bias, (size_t)o, f32);
    #pragma unroll
    for (int rg = 0; rg < 4; ++rg) {
        const int p = p0 + row4 + rg;
        dst[((size_t)(n * NHEAD + h) * HW + p) * HD + d] = __float2bfloat16((acc[rg] + bv) * scale);
    }
}

// ---------------- Kernel 3: fused local attention ----------------
// Wave = one query. lane = (w16 = lane>>2 in 0..15, qq = lane&3 = d-quarter).
__global__ __launch_bounds__(256) void attn_kernel(
    const __hip_bfloat16* __restrict__ qs, const __hip_bfloat16* __restrict__ ks,
    const __hip_bfloat16* __restrict__ vs,
    const void* __restrict__ rkw, const void* __restrict__ rkb,
    const void* __restrict__ relv, const int* __restrict__ flag,
    __hip_bfloat16* __restrict__ agg,   // [hw, n, 256] bf16
    void* __restrict__ dout)
{
    __shared__ float sL[4][240];
    __shared__ __hip_bfloat16 sRv[WS2 * 40];   // relv transposed: [w][d], d-stride padded to 40

    const bool f32 = (*flag != 0);
    const int wave = threadIdx.x >> 6, lane = threadIdx.x & 63;
    const int qidx = blockIdx.x * 4 + wave;     // (n*NH+h)*HW + i  (block never spans heads)
    const int i = qidx % HW, nh_ = qidx / HW;
    const int h = nh_ & (NHEAD - 1), n = nh_ >> 3;
    const int y = i / WDIM, x = i - y * WDIM;

    // stage relv[h][d][w] -> sRv[w*40+d]  (head is uniform across the block)
    for (int idx = threadIdx.x; idx < WS2 * HD; idx += 256) {
        const int d = idx / WS2, w = idx - d * WS2;
        sRv[w * 40 + d] = __float2bfloat16(ldf(relv, (size_t)(h * HD + d) * WS2 + w, f32));
    }
    __syncthreads();

    const int w16 = lane >> 2, qq = lane & 3;
    float q8[8];
    {
        short8 qv = *(const short8*)(qs + (size_t)qidx * HD + qq * 8);
        #pragma unroll
        for (int t = 0; t < 8; ++t) q8[t] = bu2f(qv[t]);
    }

    // ---- phase B: logits ----
    const int kxu = x + w16 - 7;
    const bool vw = (w16 < 15);
    for (int r = 0; r < 15; ++r) {
        const int ky = y + r - 7;
        const int widx = r * 15 + w16;
        const bool vimg = vw && ((unsigned)ky < WDIM) && ((unsigned)kxu < WDIM);
        float part = 0.f;
        if (vimg) {
            short8 kv = *(const short8*)(ks + ((size_t)nh_ * HW + ky * WDIM + kxu) * HD + qq * 8);
            float r8[8];
            ld8f(rkw, ((size_t)h * WS2 + widx) * HD + qq * 8, f32, r8);
            #pragma unroll
            for (int t = 0; t < 8; ++t) part += q8[t] * (bu2f(kv[t]) + TSC * r8[t]);
        }
        part += __shfl_xor(part, 1);
        part += __shfl_xor(part, 2);
        if (qq == 0) {
            float lg = vimg ? (part + ldf(rkb, (size_t)h * WS2 + widx, f32)) : -1e30f;
            sL[wave][vw ? widx : (225 + r)] = lg;   // dummy lane fills pad slot 225+r
        }
    }

    // ---- phase C: softmax over 225 (same-wave LDS, no barrier needed) ----
    float lg[4];
    float mx = -1e30f;
    #pragma unroll
    for (int c = 0; c < 4; ++c) {
        const int w_ = lane + 64 * c;
        lg[c] = (w_ < 240) ? sL[wave][w_] : -1e30f;
        mx = fmaxf(mx, lg[c]);
    }
    #pragma unroll
    for (int off = 32; off > 0; off >>= 1) mx = fmaxf(mx, __shfl_xor(mx, off));
    float s = 0.f;
    #pragma unroll
    for (int c = 0; c < 4; ++c) { lg[c] = expf(lg[c] - mx); s += lg[c]; }
    #pragma unroll
    for (int off = 32; off > 0; off >>= 1) s += __shfl_xor(s, off);
    const float inv = (s > 0.f) ? (1.0f / s) : 0.f;
    #pragma unroll
    for (int c = 0; c < 4; ++c) {
        const int w_ = lane + 64 * c;
        if (w_ < WS2) {
            const float a = lg[c] * inv;
            sL[wave][w_] = a;
            st_out(dout, (size_t)PROJ + (size_t)qidx * WS2 + w_, a, f32);
        }
    }

    // ---- phase D: O[d] = sum_w P[w]*(V[j(w)][d] + relv_t[w][d]) ----
    // out-of-image w have P == exact 0 (exp underflow), so only index-clamp is needed.
    float o8[8] = {0.f, 0.f, 0.f, 0.f, 0.f, 0.f, 0.f, 0.f};
    for (int r = 0; r < 15; ++r) {
        if (vw) {
            const int widx = r * 15 + w16;
            int ky = y + r - 7;
            int kyc = min(max(ky, 0), WDIM - 1);
            int kxc = min(max(kxu, 0), WDIM - 1);
            const float P = sL[wave][widx];
            short8 vv = *(const short8*)(vs + ((size_t)nh_ * HW + kyc * WDIM + kxc) * HD + qq * 8);
            short8 rv = *(const short8*)(sRv + widx * 40 + qq * 8);
            #pragma unroll
            for (int t = 0; t < 8; ++t) o8[t] += P * (bu2f(vv[t]) + bu2f(rv[t]));
        }
    }
    #pragma unroll
    for (int off = 4; off <= 32; off <<= 1)
        #pragma unroll
        for (int t = 0; t < 8; ++t) o8[t] += __shfl_xor(o8[t], off);
    if (lane < 4) {                       // w16==0, qq = lane
        short8 tmp;
        #pragma unroll
        for (int t = 0; t < 8; ++t) tmp[t] = f2bu(o8[t]);
        *(short8*)(agg + ((size_t)i * NB + n) * CDIM + h * HD + qq * 8) = tmp;
    }
}

// ---------------- Kernel 4: output projection via MFMA ----------------
// out[rb][o] = sum_c agg[rb][c]*Wp[o][c] + bp[o]
__global__ __launch_bounds__(256) void out_mfma(
    const __hip_bfloat16* __restrict__ agg, const void* __restrict__ Wp,
    const void* __restrict__ bp, const int* __restrict__ flag,
    void* __restrict__ dout)
{
    const bool f32 = (*flag != 0);
    const int wave = threadIdx.x >> 6, lane = threadIdx.x & 63;
    const int tile = blockIdx.x * 4 + wave;          // 3200 tiles = 200rb * 16o
    const int rb0 = tile & ~15;
    const int o0 = (tile & 15) << 4;
    const int m = lane & 15, q = lane >> 4;

    const __hip_bfloat16* arow = agg + (size_t)(rb0 + m) * CDIM + q * 8;
    const size_t bidx = (size_t)(o0 + m) * CDIM + q * 8;

    floatx4 acc = {0.f, 0.f, 0.f, 0.f};
    #pragma unroll
    for (int k = 0; k < 8; ++k) {
        short8 a = *(const short8*)(arow + k * 32);
        short8 b = ld8bf(Wp, bidx + k * 32, f32);
        acc = __builtin_amdgcn_mfma_f32_16x16x32_bf16(a, b, acc, 0, 0, 0);
    }
    const int col = lane & 15, row4 = (lane >> 4) * 4;
    const int o = o0 + col;
    const float bv = ldf(bp, (size_t)o, f32);
    #pragma unroll
    for (int rg = 0; rg < 4; ++rg) {
        const int rb = rb0 + row4 + rg;
        st_out(dout, (size_t)rb * CDIM + o, acc[rg] + bv, f32);
    }
}

extern "C" void kernel_launch(void* const* d_in, const int* in_sizes, int n_in,
                              void* d_out, int out_size, void* d_ws, size_t ws_size,
                              hipStream_t stream)
{
    const void* q   = d_in[0];
    const void* k   = d_in[1];
    const void* v   = d_in[2];
    const void* Wq  = d_in[3];
    const void* bq  = d_in[4];
    const void* Wk  = d_in[5];
    const void* bk  = d_in[6];
    const void* Wv  = d_in[7];
    const void* bv  = d_in[8];
    const void* rkw = d_in[9];
    const void* rkb = d_in[10];
    const void* rlv = d_in[11];
    const void* Wp  = d_in[12];
    const void* bp  = d_in[13];

    // workspace (6.554 MB, same as proven-safe round 2):
    // flag(64B) | qs | ks | vs | XtAgg   (each PROJ bf16 elems; XtAgg serves
    // as the x-transpose buffer during projections, then as agg afterwards)
    char* wsb = (char*)d_ws;
    int* flag = (int*)wsb;
    __hip_bfloat16* qs    = (__hip_bfloat16*)(wsb + 64);
    __hip_bfloat16* ks    = qs + PROJ;
    __hip_bfloat16* vs    = ks + PROJ;
    __hip_bfloat16* xtagg = vs + PROJ;

    detect_kernel<<<1, 64, 0, stream>>>(q, flag);

    const void* xs[3] = {q, k, v};
    const void* Ws[3] = {Wq, Wk, Wv};
    const void* bs[3] = {bq, bk, bv};
    __hip_bfloat16* dsts[3] = {qs, ks, vs};
    const float scales[3] = {0.17677669529663687f, 1.0f, 1.0f};
    for (int t = 0; t < 3; ++t) {
        tx_kernel<<<dim3(50, 8, 2), 256, 0, stream>>>(xs[t], flag, xtagg);
        proj_mfma<<<800, 256, 0, stream>>>(xtagg, Ws[t], bs[t], flag, dsts[t], scales[t]);
    }
    attn_kernel<<<6400, 256, 0, stream>>>(qs, ks, vs, rkw, rkb, rlv, flag, xtagg, d_out);
    out_mfma<<<800, 256, 0, stream>>>(xtagg, Wp, bp, flag, d_out);
}

// Round 4
// 235.160 us; speedup vs baseline: 2.7487x; 1.0977x over previous
//
#include <hip/hip_runtime.h>
#include <hip/hip_bf16.h>

#define HW    1600
#define NB    2
#define NHEAD 8
#define HD    32
#define WS2   225
#define WDIM  40
#define CDIM  256
#define PROJ  819200                 // NB*NHEAD*HW*HD elements
#define RELW  240                    // padded w-stride of rel buffer
#define TSC   5.656854249492381f     // sqrt(32)

typedef __attribute__((ext_vector_type(8))) short short8;
typedef __attribute__((ext_vector_type(4))) float floatx4;

static __device__ __forceinline__ float bu2f(short u) {
    return __uint_as_float(((unsigned)(unsigned short)u) << 16);
}
static __device__ __forceinline__ short f2bu(float f) {
    __hip_bfloat16 h = __float2bfloat16(f);
    short s; __builtin_memcpy(&s, &h, 2); return s;
}
static __device__ __forceinline__ float ldf(const void* p, size_t i, bool f32) {
    return f32 ? ((const float*)p)[i] : __bfloat162float(((const __hip_bfloat16*)p)[i]);
}
static __device__ __forceinline__ void st_out(void* p, size_t i, float v, bool f32) {
    if (f32) ((float*)p)[i] = v;
    else     ((__hip_bfloat16*)p)[i] = __float2bfloat16(v);
}
static __device__ __forceinline__ short8 ld8bf(const void* p, size_t i, bool f32) {
    if (!f32) return *(const short8*)((const __hip_bfloat16*)p + i);
    const float* f = (const float*)p + i;
    short8 r;
    #pragma unroll
    for (int t = 0; t < 8; ++t) r[t] = f2bu(f[t]);
    return r;
}
static __device__ __forceinline__ void ld8f(const void* p, size_t i, bool f32, float* o) {
    if (f32) {
        const float* f = (const float*)p + i;
        #pragma unroll
        for (int t = 0; t < 8; ++t) o[t] = f[t];
    } else {
        short8 s = *(const short8*)((const __hip_bfloat16*)p + i);
        #pragma unroll
        for (int t = 0; t < 8; ++t) o[t] = bu2f(s[t]);
    }
}

// ---------------- Kernel 0: input dtype detection ----------------
__global__ __launch_bounds__(64) void detect_kernel(const void* qv, int* flag) {
    const __hip_bfloat16* qb = (const __hip_bfloat16*)qv;
    int bad = 0;
    for (int i = threadIdx.x; i < 4096; i += 64) {
        float v = __bfloat162float(qb[i]);
        if (!(v > -1e6f && v < 1e6f)) bad = 1;
    }
    bad = (__any(bad) ? 1 : 0);
    if (threadIdx.x == 0) *flag = bad;
}

// ---------------- Kernel 1: relv [h][d][w] -> relvT [h][w][d] bf16 ----------------
__global__ __launch_bounds__(256) void relvT_kernel(const void* __restrict__ relv,
                                                    const int* __restrict__ flag,
                                                    __hip_bfloat16* __restrict__ relvT) {
    const bool f32 = (*flag != 0);
    const int h = blockIdx.x;
    for (int idx = threadIdx.x; idx < WS2 * HD; idx += 256) {
        const int w = idx >> 5, d = idx & 31;
        relvT[(size_t)h * WS2 * HD + idx] =
            __float2bfloat16(ldf(relv, ((size_t)h * HD + d) * WS2 + w, f32));
    }
}

// ---------------- Kernel 2: fused transpose + projection GEMM (q,k,v) -------------
// grid (50 m-blocks, 2 n, 3 t), block 256. Per block: C[32p x 256o] = X^T * W^T + b.
// X-tile transposed into LDS (row stride 264 elems = even bank spread for b128 reads).
__global__ __launch_bounds__(256) void proj_fused(
    const void* __restrict__ xq, const void* __restrict__ xk, const void* __restrict__ xv,
    const void* __restrict__ Wq, const void* __restrict__ bq,
    const void* __restrict__ Wk, const void* __restrict__ bk,
    const void* __restrict__ Wv, const void* __restrict__ bv,
    const int* __restrict__ flag,
    __hip_bfloat16* __restrict__ qs, __hip_bfloat16* __restrict__ ks,
    __hip_bfloat16* __restrict__ vs)
{
    __shared__ short xt[32][264];
    const bool f32 = (*flag != 0);
    const int m0 = blockIdx.x * 32;
    const int n  = blockIdx.y;
    const int t  = blockIdx.z;
    const void *x, *W, *bias; __hip_bfloat16* dst; float scale;
    if (t == 0)      { x = xq; W = Wq; bias = bq; dst = qs; scale = 0.17677669529663687f; }
    else if (t == 1) { x = xk; W = Wk; bias = bk; dst = ks; scale = 1.f; }
    else             { x = xv; W = Wv; bias = bv; dst = vs; scale = 1.f; }

    {   // load 32 p-contiguous elems of channel c, scatter transposed into LDS
        const int c = threadIdx.x;
        const size_t xb = ((size_t)n * CDIM + c) * HW + m0;
        if (f32) {
            const float* xr = (const float*)x + xb;
            #pragma unroll
            for (int g = 0; g < 8; ++g) {
                float4 f = *(const float4*)(xr + g * 4);
                xt[g*4+0][c] = f2bu(f.x); xt[g*4+1][c] = f2bu(f.y);
                xt[g*4+2][c] = f2bu(f.z); xt[g*4+3][c] = f2bu(f.w);
            }
        } else {
            const __hip_bfloat16* xr = (const __hip_bfloat16*)x + xb;
            #pragma unroll
            for (int g = 0; g < 4; ++g) {
                short8 s = *(const short8*)(xr + g * 8);
                #pragma unroll
                for (int u = 0; u < 8; ++u) xt[g*8+u][c] = s[u];
            }
        }
    }
    __syncthreads();

    const int wave = threadIdx.x >> 6, lane = threadIdx.x & 63;
    const int m = lane & 15, qd = lane >> 4;

    short8 A[2][8];
    #pragma unroll
    for (int mt = 0; mt < 2; ++mt)
        #pragma unroll
        for (int k = 0; k < 8; ++k)
            A[mt][k] = *(const short8*)(&xt[mt*16 + m][k*32 + qd*8]);

    #pragma unroll
    for (int og = 0; og < 4; ++og) {
        const int o0 = (wave * 4 + og) * 16;
        short8 B[8];
        #pragma unroll
        for (int k = 0; k < 8; ++k)
            B[k] = ld8bf(W, (size_t)(o0 + m) * CDIM + k*32 + qd*8, f32);
        floatx4 acc0 = {0,0,0,0}, acc1 = {0,0,0,0};
        #pragma unroll
        for (int k = 0; k < 8; ++k) {
            acc0 = __builtin_amdgcn_mfma_f32_16x16x32_bf16(A[0][k], B[k], acc0, 0, 0, 0);
            acc1 = __builtin_amdgcn_mfma_f32_16x16x32_bf16(A[1][k], B[k], acc1, 0, 0, 0);
        }
        const int o = o0 + (lane & 15), h = o >> 5, d = o & 31;
        const float bv_ = ldf(bias, (size_t)o, f32);
        #pragma unroll
        for (int rg = 0; rg < 4; ++rg) {
            const int p = m0 + (lane >> 4) * 4 + rg;
            dst[((size_t)(n*NHEAD + h)*HW + p)*HD + d]      = __float2bfloat16((acc0[rg] + bv_) * scale);
            dst[((size_t)(n*NHEAD + h)*HW + p + 16)*HD + d] = __float2bfloat16((acc1[rg] + bv_) * scale);
        }
    }
}

// ---------------- Kernel 3: rel GEMM via MFMA ----------------
// rel[nh][i][w] = T * (qs[nh][i][:] . rkw[h][w][:]) + rkb[h][w], bf16, w-stride 240.
__global__ __launch_bounds__(256) void rel_gemm(
    const __hip_bfloat16* __restrict__ qs, const void* __restrict__ rkw,
    const void* __restrict__ rkb, const int* __restrict__ flag,
    __hip_bfloat16* __restrict__ rel)
{
    const bool f32 = (*flag != 0);
    const int wave = threadIdx.x >> 6, lane = threadIdx.x & 63;
    const int i0 = blockIdx.x * 64;
    const int nh_ = blockIdx.y;
    const int h = nh_ & 7;
    const int m = lane & 15, qd = lane >> 4;

    short8 A[4];
    #pragma unroll
    for (int it = 0; it < 4; ++it)
        A[it] = *(const short8*)(qs + ((size_t)nh_ * HW + i0 + it*16 + m) * HD + qd*8);

    for (int wt = wave; wt < 15; wt += 4) {
        const int w0 = wt * 16;
        const int wl = min(w0 + m, WS2 - 1);
        short8 B = ld8bf(rkw, ((size_t)h * WS2 + wl) * HD + qd*8, f32);
        const int wcol = w0 + (lane & 15);
        const float rb_ = (wcol < WS2) ? ldf(rkb, (size_t)h * WS2 + wcol, f32) : 0.f;
        #pragma unroll
        for (int it = 0; it < 4; ++it) {
            floatx4 acc = {0,0,0,0};
            acc = __builtin_amdgcn_mfma_f32_16x16x32_bf16(A[it], B, acc, 0, 0, 0);
            if (wcol < WS2) {
                #pragma unroll
                for (int rg = 0; rg < 4; ++rg) {
                    const int i = i0 + it*16 + (lane >> 4)*4 + rg;
                    rel[((size_t)nh_ * HW + i) * RELW + wcol] =
                        __float2bfloat16(acc[rg] * TSC + rb_);
                }
            }
        }
    }
}

// ---------------- Kernel 4: fused local attention ----------------
// Wave = one query. lane = (w16 = lane>>2 in 0..15, qq = lane&3 = d-quarter).
template<int USEREL>
__global__ __launch_bounds__(256) void attn_kernel(
    const __hip_bfloat16* __restrict__ qs, const __hip_bfloat16* __restrict__ ks,
    const __hip_bfloat16* __restrict__ vs,
    const __hip_bfloat16* __restrict__ rel,     // [nh*1600, 240] (USEREL=1)
    const __hip_bfloat16* __restrict__ relvT,   // [h][w][d]
    const void* __restrict__ rkw, const void* __restrict__ rkb,  // fallback path
    const int* __restrict__ flag,
    __hip_bfloat16* __restrict__ agg,           // [hw, n, 256]
    void* __restrict__ dout)
{
    __shared__ float sL[4][240];

    const bool f32 = (*flag != 0);
    const int wave = threadIdx.x >> 6, lane = threadIdx.x & 63;
    const int qidx = blockIdx.x * 4 + wave;      // (n*NH+h)*HW + i
    const int i = qidx % HW, nh_ = qidx / HW;
    const int h = nh_ & (NHEAD - 1), n = nh_ >> 3;
    const int y = i / WDIM, x = i - y * WDIM;

    const int w16 = lane >> 2, qq = lane & 3;
    float q8[8];
    {
        short8 qv = *(const short8*)(qs + (size_t)qidx * HD + qq * 8);
        #pragma unroll
        for (int t = 0; t < 8; ++t) q8[t] = bu2f(qv[t]);
    }

    // ---- phase B: logits ----
    const int kxu = x + w16 - 7;
    const bool vw = (w16 < 15);
    for (int r = 0; r < 15; ++r) {
        const int ky = y + r - 7;
        const int widx = r * 15 + w16;
        const bool vimg = vw && ((unsigned)ky < WDIM) && ((unsigned)kxu < WDIM);
        float part = 0.f;
        if (vimg) {
            short8 kv = *(const short8*)(ks + ((size_t)nh_ * HW + ky * WDIM + kxu) * HD + qq * 8);
            if (USEREL) {
                #pragma unroll
                for (int t = 0; t < 8; ++t) part += q8[t] * bu2f(kv[t]);
            } else {
                float r8[8];
                ld8f(rkw, ((size_t)h * WS2 + widx) * HD + qq * 8, f32, r8);
                #pragma unroll
                for (int t = 0; t < 8; ++t) part += q8[t] * (bu2f(kv[t]) + TSC * r8[t]);
            }
        }
        part += __shfl_xor(part, 1);
        part += __shfl_xor(part, 2);
        if (qq == 0) {
            float lg = -1e30f;
            if (vimg) {
                const float rb_ = USEREL
                    ? __bfloat162float(rel[(size_t)qidx * RELW + widx])
                    : ldf(rkb, (size_t)h * WS2 + widx, f32);
                lg = part + rb_;
            }
            sL[wave][vw ? widx : (225 + r)] = lg;   // dummy lane fills pad slot
        }
    }

    // ---- phase C: softmax over 225 (same-wave LDS) ----
    float lg[4];
    float mx = -1e30f;
    #pragma unroll
    for (int c = 0; c < 4; ++c) {
        const int w_ = lane + 64 * c;
        lg[c] = (w_ < 240) ? sL[wave][w_] : -1e30f;
        mx = fmaxf(mx, lg[c]);
    }
    #pragma unroll
    for (int off = 32; off > 0; off >>= 1) mx = fmaxf(mx, __shfl_xor(mx, off));
    float s = 0.f;
    #pragma unroll
    for (int c = 0; c < 4; ++c) { lg[c] = expf(lg[c] - mx); s += lg[c]; }
    #pragma unroll
    for (int off = 32; off > 0; off >>= 1) s += __shfl_xor(s, off);
    const float inv = (s > 0.f) ? (1.0f / s) : 0.f;
    #pragma unroll
    for (int c = 0; c < 4; ++c) {
        const int w_ = lane + 64 * c;
        if (w_ < WS2) {
            const float a = lg[c] * inv;
            sL[wave][w_] = a;
            st_out(dout, (size_t)PROJ + (size_t)qidx * WS2 + w_, a, f32);
        }
    }

    // ---- phase D: O[d] = sum_w P[w]*(V[j(w)][d] + relvT[w][d]) ----
    float o8[8] = {0.f, 0.f, 0.f, 0.f, 0.f, 0.f, 0.f, 0.f};
    if (vw) {
        for (int r = 0; r < 15; ++r) {
            const int widx = r * 15 + w16;
            const int kyc = min(max(y + r - 7, 0), WDIM - 1);
            const int kxc = min(max(kxu, 0), WDIM - 1);
            const float P = sL[wave][widx];   // exact 0 for out-of-image slots
            short8 vv = *(const short8*)(vs + ((size_t)nh_ * HW + kyc * WDIM + kxc) * HD + qq * 8);
            short8 rv = *(const short8*)(relvT + ((size_t)h * WS2 + widx) * HD + qq * 8);
            #pragma unroll
            for (int t = 0; t < 8; ++t) o8[t] += P * (bu2f(vv[t]) + bu2f(rv[t]));
        }
    }
    #pragma unroll
    for (int off = 4; off <= 32; off <<= 1)
        #pragma unroll
        for (int t = 0; t < 8; ++t) o8[t] += __shfl_xor(o8[t], off);
    if (lane < 4) {                       // w16==0, qq = lane
        short8 tmp;
        #pragma unroll
        for (int t = 0; t < 8; ++t) tmp[t] = f2bu(o8[t]);
        *(short8*)(agg + ((size_t)i * NB + n) * CDIM + h * HD + qq * 8) = tmp;
    }
}

// ---------------- Kernel 5: output projection via MFMA ----------------
__global__ __launch_bounds__(256) void out_mfma(
    const __hip_bfloat16* __restrict__ agg, const void* __restrict__ Wp,
    const void* __restrict__ bp, const int* __restrict__ flag,
    void* __restrict__ dout)
{
    const bool f32 = (*flag != 0);
    const int wave = threadIdx.x >> 6, lane = threadIdx.x & 63;
    const int tile = blockIdx.x * 4 + wave;          // 3200 tiles = 200rb * 16o
    const int rb0 = tile & ~15;
    const int o0 = (tile & 15) << 4;
    const int m = lane & 15, qd = lane >> 4;

    const __hip_bfloat16* arow = agg + (size_t)(rb0 + m) * CDIM + qd * 8;
    const size_t bidx = (size_t)(o0 + m) * CDIM + qd * 8;

    floatx4 acc = {0.f, 0.f, 0.f, 0.f};
    #pragma unroll
    for (int k = 0; k < 8; ++k) {
        short8 a = *(const short8*)(arow + k * 32);
        short8 b = ld8bf(Wp, bidx + k * 32, f32);
        acc = __builtin_amdgcn_mfma_f32_16x16x32_bf16(a, b, acc, 0, 0, 0);
    }
    const int o = o0 + (lane & 15);
    const float bv_ = ldf(bp, (size_t)o, f32);
    #pragma unroll
    for (int rg = 0; rg < 4; ++rg) {
        const int rb = rb0 + (lane >> 4) * 4 + rg;
        st_out(dout, (size_t)rb * CDIM + o, acc[rg] + bv_, f32);
    }
}

extern "C" void kernel_launch(void* const* d_in, const int* in_sizes, int n_in,
                              void* d_out, int out_size, void* d_ws, size_t ws_size,
                              hipStream_t stream)
{
    const void* q   = d_in[0];
    const void* k   = d_in[1];
    const void* v   = d_in[2];
    const void* Wq  = d_in[3];
    const void* bq  = d_in[4];
    const void* Wk  = d_in[5];
    const void* bk  = d_in[6];
    const void* Wv  = d_in[7];
    const void* bv  = d_in[8];
    const void* rkw = d_in[9];
    const void* rkb = d_in[10];
    const void* rlv = d_in[11];
    const void* Wp  = d_in[12];
    const void* bp  = d_in[13];

    // ws layout: flag(64B) | relvT(115200B) | qs | ks | vs | agg (PROJ bf16 each) | rel
    char* wsb = (char*)d_ws;
    int* flag = (int*)wsb;
    __hip_bfloat16* relvT = (__hip_bfloat16*)(wsb + 64);
    __hip_bfloat16* qs    = (__hip_bfloat16*)(wsb + 64 + 115200);
    __hip_bfloat16* ks    = qs + PROJ;
    __hip_bfloat16* vs    = ks + PROJ;
    __hip_bfloat16* agg   = vs + PROJ;
    __hip_bfloat16* rel   = agg + PROJ;
    const size_t need = 64 + 115200 + (size_t)4 * PROJ * 2 + (size_t)NB * NHEAD * HW * RELW * 2;
    const bool userel = (ws_size >= need);

    detect_kernel<<<1, 64, 0, stream>>>(q, flag);
    relvT_kernel<<<8, 256, 0, stream>>>(rlv, flag, relvT);
    proj_fused<<<dim3(50, 2, 3), 256, 0, stream>>>(q, k, v, Wq, bq, Wk, bk, Wv, bv,
                                                   flag, qs, ks, vs);
    if (userel) {
        rel_gemm<<<dim3(25, 16), 256, 0, stream>>>(qs, rkw, rkb, flag, rel);
        attn_kernel<1><<<6400, 256, 0, stream>>>(qs, ks, vs, rel, relvT, rkw, rkb, flag, agg, d_out);
    } else {
        attn_kernel<0><<<6400, 256, 0, stream>>>(qs, ks, vs, rel, relvT, rkw, rkb, flag, agg, d_out);
    }
    out_mfma<<<800, 256, 0, stream>>>(agg, Wp, bp, flag, d_out);
}

// Round 5
// 207.799 us; speedup vs baseline: 3.1107x; 1.1317x over previous
//
#include <hip/hip_runtime.h>
#include <hip/hip_bf16.h>

#define HW    1600
#define NB    2
#define NHEAD 8
#define HD    32
#define WS2   225
#define WDIM  40
#define CDIM  256
#define PROJ  819200                 // NB*NHEAD*HW*HD elements
#define RELW  240                    // padded w-stride of rel buffer
#define TSC   5.656854249492381f     // sqrt(32)

typedef __attribute__((ext_vector_type(8))) short short8;
typedef __attribute__((ext_vector_type(4))) float floatx4;

static __device__ __forceinline__ float bu2f(short u) {
    return __uint_as_float(((unsigned)(unsigned short)u) << 16);
}
static __device__ __forceinline__ short f2bu(float f) {
    __hip_bfloat16 h = __float2bfloat16(f);
    short s; __builtin_memcpy(&s, &h, 2); return s;
}
static __device__ __forceinline__ unsigned pk2(short a, short b) {
    return (unsigned)(unsigned short)a | ((unsigned)(unsigned short)b << 16);
}
static __device__ __forceinline__ float ldf(const void* p, size_t i, bool f32) {
    return f32 ? ((const float*)p)[i] : __bfloat162float(((const __hip_bfloat16*)p)[i]);
}
static __device__ __forceinline__ void st_out(void* p, size_t i, float v, bool f32) {
    if (f32) ((float*)p)[i] = v;
    else     ((__hip_bfloat16*)p)[i] = __float2bfloat16(v);
}
static __device__ __forceinline__ short8 ld8bf(const void* p, size_t i, bool f32) {
    if (!f32) return *(const short8*)((const __hip_bfloat16*)p + i);
    const float* f = (const float*)p + i;
    short8 r;
    #pragma unroll
    for (int t = 0; t < 8; ++t) r[t] = f2bu(f[t]);
    return r;
}
static __device__ __forceinline__ void ld8f(const void* p, size_t i, bool f32, float* o) {
    if (f32) {
        const float* f = (const float*)p + i;
        #pragma unroll
        for (int t = 0; t < 8; ++t) o[t] = f[t];
    } else {
        short8 s = *(const short8*)((const __hip_bfloat16*)p + i);
        #pragma unroll
        for (int t = 0; t < 8; ++t) o[t] = bu2f(s[t]);
    }
}

// ---------------- Kernel 0: input dtype detection ----------------
__global__ __launch_bounds__(64) void detect_kernel(const void* qv, int* flag) {
    const __hip_bfloat16* qb = (const __hip_bfloat16*)qv;
    int bad = 0;
    for (int i = threadIdx.x; i < 4096; i += 64) {
        float v = __bfloat162float(qb[i]);
        if (!(v > -1e6f && v < 1e6f)) bad = 1;
    }
    bad = (__any(bad) ? 1 : 0);
    if (threadIdx.x == 0) *flag = bad;
}

// ---------------- Kernel 1: relv [h][d][w] -> relvT [h][w][d] bf16 ----------------
__global__ __launch_bounds__(256) void relvT_kernel(const void* __restrict__ relv,
                                                    const int* __restrict__ flag,
                                                    __hip_bfloat16* __restrict__ relvT) {
    const bool f32 = (*flag != 0);
    const int h = blockIdx.x;
    for (int idx = threadIdx.x; idx < WS2 * HD; idx += 256) {
        const int w = idx >> 5, d = idx & 31;
        relvT[(size_t)h * WS2 * HD + idx] =
            __float2bfloat16(ldf(relv, ((size_t)h * HD + d) * WS2 + w, f32));
    }
}

// ---------------- Kernel 2: fused transpose + projection GEMM (q,k,v) -------------
__global__ __launch_bounds__(256) void proj_fused(
    const void* __restrict__ xq, const void* __restrict__ xk, const void* __restrict__ xv,
    const void* __restrict__ Wq, const void* __restrict__ bq,
    const void* __restrict__ Wk, const void* __restrict__ bk,
    const void* __restrict__ Wv, const void* __restrict__ bv,
    const int* __restrict__ flag,
    __hip_bfloat16* __restrict__ qs, __hip_bfloat16* __restrict__ ks,
    __hip_bfloat16* __restrict__ vs)
{
    __shared__ short xt[32][264];
    const bool f32 = (*flag != 0);
    const int m0 = blockIdx.x * 32;
    const int n  = blockIdx.y;
    const int t  = blockIdx.z;
    const void *x, *W, *bias; __hip_bfloat16* dst; float scale;
    if (t == 0)      { x = xq; W = Wq; bias = bq; dst = qs; scale = 0.17677669529663687f; }
    else if (t == 1) { x = xk; W = Wk; bias = bk; dst = ks; scale = 1.f; }
    else             { x = xv; W = Wv; bias = bv; dst = vs; scale = 1.f; }

    {
        const int c = threadIdx.x;
        const size_t xb = ((size_t)n * CDIM + c) * HW + m0;
        if (f32) {
            const float* xr = (const float*)x + xb;
            #pragma unroll
            for (int g = 0; g < 8; ++g) {
                float4 f = *(const float4*)(xr + g * 4);
                xt[g*4+0][c] = f2bu(f.x); xt[g*4+1][c] = f2bu(f.y);
                xt[g*4+2][c] = f2bu(f.z); xt[g*4+3][c] = f2bu(f.w);
            }
        } else {
            const __hip_bfloat16* xr = (const __hip_bfloat16*)x + xb;
            #pragma unroll
            for (int g = 0; g < 4; ++g) {
                short8 s = *(const short8*)(xr + g * 8);
                #pragma unroll
                for (int u = 0; u < 8; ++u) xt[g*8+u][c] = s[u];
            }
        }
    }
    __syncthreads();

    const int wave = threadIdx.x >> 6, lane = threadIdx.x & 63;
    const int m = lane & 15, qd = lane >> 4;

    short8 A[2][8];
    #pragma unroll
    for (int mt = 0; mt < 2; ++mt)
        #pragma unroll
        for (int k = 0; k < 8; ++k)
            A[mt][k] = *(const short8*)(&xt[mt*16 + m][k*32 + qd*8]);

    #pragma unroll
    for (int og = 0; og < 4; ++og) {
        const int o0 = (wave * 4 + og) * 16;
        short8 B[8];
        #pragma unroll
        for (int k = 0; k < 8; ++k)
            B[k] = ld8bf(W, (size_t)(o0 + m) * CDIM + k*32 + qd*8, f32);
        floatx4 acc0 = {0,0,0,0}, acc1 = {0,0,0,0};
        #pragma unroll
        for (int k = 0; k < 8; ++k) {
            acc0 = __builtin_amdgcn_mfma_f32_16x16x32_bf16(A[0][k], B[k], acc0, 0, 0, 0);
            acc1 = __builtin_amdgcn_mfma_f32_16x16x32_bf16(A[1][k], B[k], acc1, 0, 0, 0);
        }
        const int o = o0 + (lane & 15), h = o >> 5, d = o & 31;
        const float bv_ = ldf(bias, (size_t)o, f32);
        #pragma unroll
        for (int rg = 0; rg < 4; ++rg) {
            const int p = m0 + (lane >> 4) * 4 + rg;
            dst[((size_t)(n*NHEAD + h)*HW + p)*HD + d]      = __float2bfloat16((acc0[rg] + bv_) * scale);
            dst[((size_t)(n*NHEAD + h)*HW + p + 16)*HD + d] = __float2bfloat16((acc1[rg] + bv_) * scale);
        }
    }
}

// ---------------- Kernel 3: rel GEMM via MFMA ----------------
__global__ __launch_bounds__(256) void rel_gemm(
    const __hip_bfloat16* __restrict__ qs, const void* __restrict__ rkw,
    const void* __restrict__ rkb, const int* __restrict__ flag,
    __hip_bfloat16* __restrict__ rel)
{
    const bool f32 = (*flag != 0);
    const int wave = threadIdx.x >> 6, lane = threadIdx.x & 63;
    const int i0 = blockIdx.x * 64;
    const int nh_ = blockIdx.y;
    const int h = nh_ & 7;
    const int m = lane & 15, qd = lane >> 4;

    short8 A[4];
    #pragma unroll
    for (int it = 0; it < 4; ++it)
        A[it] = *(const short8*)(qs + ((size_t)nh_ * HW + i0 + it*16 + m) * HD + qd*8);

    for (int wt = wave; wt < 15; wt += 4) {
        const int w0 = wt * 16;
        const int wl = min(w0 + m, WS2 - 1);
        short8 B = ld8bf(rkw, ((size_t)h * WS2 + wl) * HD + qd*8, f32);
        const int wcol = w0 + (lane & 15);
        const float rb_ = (wcol < WS2) ? ldf(rkb, (size_t)h * WS2 + wcol, f32) : 0.f;
        #pragma unroll
        for (int it = 0; it < 4; ++it) {
            floatx4 acc = {0,0,0,0};
            acc = __builtin_amdgcn_mfma_f32_16x16x32_bf16(A[it], B, acc, 0, 0, 0);
            if (wcol < WS2) {
                #pragma unroll
                for (int rg = 0; rg < 4; ++rg) {
                    const int i = i0 + it*16 + (lane >> 4)*4 + rg;
                    rel[((size_t)nh_ * HW + i) * RELW + wcol] =
                        __float2bfloat16(acc[rg] * TSC + rb_);
                }
            }
        }
    }
}

// ---------------- Kernel 4: full-MFMA fused local attention ----------------
// Block = 16-query x-strip (n,h,y,x0). S = Q·K^T (30 MFMAs over padded 15x32 window),
// rel added per-element from the precomputed rel buffer, block softmax, then
// PV + rel_v as 23 MFMAs against LDS-staged P (kk- and w-space) and V^T/Rv^T
// (d staged in halves of 16 to keep LDS at 48.6 KB -> 3 blocks/CU).
#define SP_OFF    0        // sP  [16][488] bf16 (kk-space P)
#define SPW_OFF   15616    // sPw [16][264] bf16 (w-space P)
#define STAGE_OFF 24064    // sVTh [16][488] bf16 (V^T rows d-half)  / sOh alias (f32[4][16][16])
#define RVT_OFF   39680    // sRvTh [16][264] bf16
#define SMAX_OFF  48128    // f32[64]
#define SSUM_OFF  48384    // f32[64]
#define SMEM_SZ   48640

__global__ __launch_bounds__(256) void attn_mfma(
    const __hip_bfloat16* __restrict__ qs, const __hip_bfloat16* __restrict__ ks,
    const __hip_bfloat16* __restrict__ vs,
    const __hip_bfloat16* __restrict__ rel,     // [nh*1600, 240]
    const __hip_bfloat16* __restrict__ relvT,   // [h][w][d]
    const int* __restrict__ flag,
    __hip_bfloat16* __restrict__ agg,           // [hw, n, 256]
    void* __restrict__ dout)
{
    __shared__ __align__(16) char smem[SMEM_SZ];
    short* sP  = (short*)(smem + SP_OFF);
    short* sPw = (short*)(smem + SPW_OFF);
    float* sMax = (float*)(smem + SMAX_OFF);
    float* sSum = (float*)(smem + SSUM_OFF);

    const bool f32 = (*flag != 0);
    const int tid = threadIdx.x;
    const int wave = tid >> 6, lane = tid & 63;
    const int m = lane & 15, quad = lane >> 4;
    const int y = blockIdx.x / 3, tile3 = blockIdx.x % 3;
    const int x0 = (tile3 == 0) ? 0 : (tile3 == 1) ? 16 : 24;
    const int wlo = (tile3 == 2) ? 8 : 0;
    const int nh_ = blockIdx.y;
    const int h = nh_ & 7, n = nh_ >> 3;
    const size_t qb = (size_t)nh_ * HW;

    // zero-init w-space P (pad cols too)
    {
        unsigned* pw32 = (unsigned*)sPw;
        for (int e = tid; e < 16 * 264 / 2; e += 256) pw32[e] = 0u;
    }
    // blanket-zero owned attn_out rows (invalid slots stay 0; valid overwritten later)
    {
        const int nq = 16 - wlo;
        for (int e = tid; e < nq * WS2; e += 256) {
            const int qq = wlo + e / WS2, w2 = e - (qq - wlo) * WS2;
            st_out(dout, (size_t)PROJ + (qb + (size_t)y * WDIM + x0 + qq) * WS2 + w2, 0.f, f32);
        }
    }

    // ---- S = Q.K^T + rel ----
    const short8 afrag = *(const short8*)((const short*)qs + (qb + (size_t)y * WDIM + x0 + m) * HD + quad * 8);

    float L[8][4];
    #pragma unroll
    for (int j = 0; j < 8; ++j)
        #pragma unroll
        for (int rg = 0; rg < 4; ++rg) L[j][rg] = -1e30f;

    #pragma unroll
    for (int j = 0; j < 8; ++j) {
        const int t = wave + 4 * j;
        if (t < 30) {
            const int r = t >> 1, c0_ = (t & 1) << 4;
            const int cc = c0_ + m;                 // key col 0..31 (== D col for this lane)
            const int ky = y + r - 7, kx = x0 - 7 + cc;
            const int gky = min(max(ky, 0), WDIM - 1), gkx = min(max(kx, 0), WDIM - 1);
            const short8 bfrag = *(const short8*)((const short*)ks + (qb + (size_t)gky * WDIM + gkx) * HD + quad * 8);
            floatx4 s4 = {0.f, 0.f, 0.f, 0.f};
            s4 = __builtin_amdgcn_mfma_f32_16x16x32_bf16(afrag, bfrag, s4, 0, 0, 0);
            const bool inimg = ((unsigned)ky < (unsigned)WDIM) && ((unsigned)kx < (unsigned)WDIM);
            #pragma unroll
            for (int rg = 0; rg < 4; ++rg) {
                const int qm = quad * 4 + rg;
                const int dx7 = cc - qm;            // widx_x
                if (inimg && (unsigned)dx7 < 15u) {
                    const int widx = r * 15 + dx7;
                    const float grel = bu2f(((const short*)rel)[(qb + (size_t)y * WDIM + x0 + qm) * RELW + widx]);
                    L[j][rg] = s4[rg] + grel;
                }
            }
        }
    }

    // ---- block softmax over each query row ----
    float mx[4];
    #pragma unroll
    for (int rg = 0; rg < 4; ++rg) {
        mx[rg] = L[0][rg];
        #pragma unroll
        for (int j = 1; j < 8; ++j) mx[rg] = fmaxf(mx[rg], L[j][rg]);
        #pragma unroll
        for (int off = 1; off <= 8; off <<= 1) mx[rg] = fmaxf(mx[rg], __shfl_xor(mx[rg], off));
    }
    if (m == 0) {
        #pragma unroll
        for (int rg = 0; rg < 4; ++rg) sMax[(quad * 4 + rg) * 4 + wave] = mx[rg];
    }
    __syncthreads();
    float M4[4], sm[4];
    #pragma unroll
    for (int rg = 0; rg < 4; ++rg) {
        const float4 v = *(const float4*)&sMax[(quad * 4 + rg) * 4];
        M4[rg] = fmaxf(fmaxf(v.x, v.y), fmaxf(v.z, v.w));
        sm[rg] = 0.f;
    }
    #pragma unroll
    for (int j = 0; j < 8; ++j)
        #pragma unroll
        for (int rg = 0; rg < 4; ++rg) { L[j][rg] = expf(L[j][rg] - M4[rg]); sm[rg] += L[j][rg]; }
    #pragma unroll
    for (int rg = 0; rg < 4; ++rg)
        #pragma unroll
        for (int off = 1; off <= 8; off <<= 1) sm[rg] += __shfl_xor(sm[rg], off);
    if (m == 0) {
        #pragma unroll
        for (int rg = 0; rg < 4; ++rg) sSum[(quad * 4 + rg) * 4 + wave] = sm[rg];
    }
    __syncthreads();
    float inv4[4];
    #pragma unroll
    for (int rg = 0; rg < 4; ++rg) {
        const float4 v = *(const float4*)&sSum[(quad * 4 + rg) * 4];
        inv4[rg] = 1.f / (v.x + v.y + v.z + v.w);
    }

    // ---- write P: kk-space (sP), w-space (sPw), attn_out (owned rows) ----
    #pragma unroll
    for (int j = 0; j < 8; ++j) {
        const int t = wave + 4 * j;
        if (t < 30) {
            const int r = t >> 1, c0_ = (t & 1) << 4;
            const int cc = c0_ + m;
            const int ky = y + r - 7, kx = x0 - 7 + cc;
            const bool inimg = ((unsigned)ky < (unsigned)WDIM) && ((unsigned)kx < (unsigned)WDIM);
            #pragma unroll
            for (int rg = 0; rg < 4; ++rg) {
                const int qm = quad * 4 + rg;
                const float p = L[j][rg] * inv4[rg];
                const short pb = f2bu(p);
                sP[qm * 488 + r * 32 + cc] = pb;
                const int dx7 = cc - qm;
                if (inimg && (unsigned)dx7 < 15u) {
                    const int widx = r * 15 + dx7;
                    sPw[qm * 264 + widx] = pb;
                    if (qm >= wlo)
                        st_out(dout, (size_t)PROJ + (qb + (size_t)y * WDIM + x0 + qm) * WS2 + widx, p, f32);
                }
            }
        }
    }

    // ---- PV + rel_v GEMMs, d staged in halves of 16 ----
    float* sOh = (float*)(smem + STAGE_OFF);
    for (int half = 0; half < 2; ++half) {
        __syncthreads();   // P writes (iter 0) / sOh reads (iter 1) complete
        const int h16 = half * 16;
        // stage V^T rows [d-half][kk 0..479] (pairs of kk packed as u32)
        {
            unsigned* dstw = (unsigned*)(smem + STAGE_OFF);
            for (int p = tid; p < 240; p += 256) {
                const int kk0 = 2 * p;
                const int r = kk0 >> 5, c = kk0 & 31;
                const int gky = min(max(y + r - 7, 0), WDIM - 1);
                const int gkx0 = min(max(x0 - 7 + c, 0), WDIM - 1);
                const int gkx1 = min(max(x0 - 7 + c + 1, 0), WDIM - 1);
                const short* v0 = (const short*)vs + (qb + (size_t)gky * WDIM + gkx0) * HD + h16;
                const short* v1 = (const short*)vs + (qb + (size_t)gky * WDIM + gkx1) * HD + h16;
                const short8 a0 = *(const short8*)v0, a1 = *(const short8*)(v0 + 8);
                const short8 b0 = *(const short8*)v1, b1 = *(const short8*)(v1 + 8);
                #pragma unroll
                for (int dd = 0; dd < 8; ++dd) dstw[dd * 244 + p] = pk2(a0[dd], b0[dd]);
                #pragma unroll
                for (int dd = 0; dd < 8; ++dd) dstw[(dd + 8) * 244 + p] = pk2(a1[dd], b1[dd]);
            }
        }
        // stage Rv^T rows [d-half][w 0..263] (w>=225 zero)
        {
            unsigned* dstw = (unsigned*)(smem + RVT_OFF);
            for (int p = tid; p < 132; p += 256) {
                const int w0 = 2 * p;
                short8 a0 = {0,0,0,0,0,0,0,0}, a1 = a0, b0 = a0, b1 = a0;
                if (w0 < WS2) {
                    const short* rp = (const short*)relvT + (size_t)h * WS2 * HD + (size_t)w0 * HD + h16;
                    a0 = *(const short8*)rp; a1 = *(const short8*)(rp + 8);
                }
                if (w0 + 1 < WS2) {
                    const short* rp = (const short*)relvT + (size_t)h * WS2 * HD + (size_t)(w0 + 1) * HD + h16;
                    b0 = *(const short8*)rp; b1 = *(const short8*)(rp + 8);
                }
                #pragma unroll
                for (int dd = 0; dd < 8; ++dd) dstw[dd * 132 + p] = pk2(a0[dd], b0[dd]);
                #pragma unroll
                for (int dd = 0; dd < 8; ++dd) dstw[(dd + 8) * 132 + p] = pk2(a1[dd], b1[dd]);
            }
        }
        __syncthreads();

        floatx4 acc = {0.f, 0.f, 0.f, 0.f};
        for (int u = wave; u < 23; u += 4) {
            const short *Ap, *Bp;
            if (u < 15) {
                Ap = sP + m * 488 + u * 32 + quad * 8;
                Bp = (const short*)(smem + STAGE_OFF) + m * 488 + u * 32 + quad * 8;
            } else {
                Ap = sPw + m * 264 + (u - 15) * 32 + quad * 8;
                Bp = (const short*)(smem + RVT_OFF) + m * 264 + (u - 15) * 32 + quad * 8;
            }
            acc = __builtin_amdgcn_mfma_f32_16x16x32_bf16(*(const short8*)Ap, *(const short8*)Bp, acc, 0, 0, 0);
        }
        __syncthreads();   // all LDS reads done before sOh alias write
        #pragma unroll
        for (int rg = 0; rg < 4; ++rg)
            sOh[wave * 256 + (quad * 4 + rg) * 16 + m] = acc[rg];
        __syncthreads();
        {
            const int qq = tid >> 4, dd = tid & 15;
            const float s = sOh[tid] + sOh[256 + tid] + sOh[512 + tid] + sOh[768 + tid];
            if (qq >= wlo) {
                const size_t i = (size_t)y * WDIM + x0 + qq;
                agg[(i * NB + n) * CDIM + h * HD + h16 + dd] = __float2bfloat16(s);
            }
        }
    }
}

// ---------------- Kernel 4b: fallback scalar attention (ws too small for rel) ------
template<int USEREL>
__global__ __launch_bounds__(256) void attn_kernel(
    const __hip_bfloat16* __restrict__ qs, const __hip_bfloat16* __restrict__ ks,
    const __hip_bfloat16* __restrict__ vs,
    const __hip_bfloat16* __restrict__ rel,
    const __hip_bfloat16* __restrict__ relvT,
    const void* __restrict__ rkw, const void* __restrict__ rkb,
    const int* __restrict__ flag,
    __hip_bfloat16* __restrict__ agg,
    void* __restrict__ dout)
{
    __shared__ float sL[4][240];

    const bool f32 = (*flag != 0);
    const int wave = threadIdx.x >> 6, lane = threadIdx.x & 63;
    const int qidx = blockIdx.x * 4 + wave;
    const int i = qidx % HW, nh_ = qidx / HW;
    const int h = nh_ & (NHEAD - 1), n = nh_ >> 3;
    const int y = i / WDIM, x = i - y * WDIM;

    const int w16 = lane >> 2, qq = lane & 3;
    float q8[8];
    {
        short8 qv = *(const short8*)(qs + (size_t)qidx * HD + qq * 8);
        #pragma unroll
        for (int t = 0; t < 8; ++t) q8[t] = bu2f(qv[t]);
    }

    const int kxu = x + w16 - 7;
    const bool vw = (w16 < 15);
    for (int r = 0; r < 15; ++r) {
        const int ky = y + r - 7;
        const int widx = r * 15 + w16;
        const bool vimg = vw && ((unsigned)ky < WDIM) && ((unsigned)kxu < WDIM);
        float part = 0.f;
        if (vimg) {
            short8 kv = *(const short8*)(ks + ((size_t)nh_ * HW + ky * WDIM + kxu) * HD + qq * 8);
            float r8[8];
            ld8f(rkw, ((size_t)h * WS2 + widx) * HD + qq * 8, f32, r8);
            #pragma unroll
            for (int t = 0; t < 8; ++t) part += q8[t] * (bu2f(kv[t]) + TSC * r8[t]);
        }
        part += __shfl_xor(part, 1);
        part += __shfl_xor(part, 2);
        if (qq == 0) {
            float lg = -1e30f;
            if (vimg) lg = part + ldf(rkb, (size_t)h * WS2 + widx, f32);
            sL[wave][vw ? widx : (225 + r)] = lg;
        }
    }

    float lg[4];
    float mx = -1e30f;
    #pragma unroll
    for (int c = 0; c < 4; ++c) {
        const int w_ = lane + 64 * c;
        lg[c] = (w_ < 240) ? sL[wave][w_] : -1e30f;
        mx = fmaxf(mx, lg[c]);
    }
    #pragma unroll
    for (int off = 32; off > 0; off >>= 1) mx = fmaxf(mx, __shfl_xor(mx, off));
    float s = 0.f;
    #pragma unroll
    for (int c = 0; c < 4; ++c) { lg[c] = expf(lg[c] - mx); s += lg[c]; }
    #pragma unroll
    for (int off = 32; off > 0; off >>= 1) s += __shfl_xor(s, off);
    const float inv = (s > 0.f) ? (1.0f / s) : 0.f;
    #pragma unroll
    for (int c = 0; c < 4; ++c) {
        const int w_ = lane + 64 * c;
        if (w_ < WS2) {
            const float a = lg[c] * inv;
            sL[wave][w_] = a;
            st_out(dout, (size_t)PROJ + (size_t)qidx * WS2 + w_, a, f32);
        }
    }

    float o8[8] = {0.f, 0.f, 0.f, 0.f, 0.f, 0.f, 0.f, 0.f};
    if (vw) {
        for (int r = 0; r < 15; ++r) {
            const int widx = r * 15 + w16;
            const int kyc = min(max(y + r - 7, 0), WDIM - 1);
            const int kxc = min(max(kxu, 0), WDIM - 1);
            const float P = sL[wave][widx];
            short8 vv = *(const short8*)(vs + ((size_t)nh_ * HW + kyc * WDIM + kxc) * HD + qq * 8);
            short8 rv = *(const short8*)(relvT + ((size_t)h * WS2 + widx) * HD + qq * 8);
            #pragma unroll
            for (int t = 0; t < 8; ++t) o8[t] += P * (bu2f(vv[t]) + bu2f(rv[t]));
        }
    }
    #pragma unroll
    for (int off = 4; off <= 32; off <<= 1)
        #pragma unroll
        for (int t = 0; t < 8; ++t) o8[t] += __shfl_xor(o8[t], off);
    if (lane < 4) {
        short8 tmp;
        #pragma unroll
        for (int t = 0; t < 8; ++t) tmp[t] = f2bu(o8[t]);
        *(short8*)(agg + ((size_t)i * NB + n) * CDIM + h * HD + qq * 8) = tmp;
    }
}

// ---------------- Kernel 5: output projection via MFMA ----------------
__global__ __launch_bounds__(256) void out_mfma(
    const __hip_bfloat16* __restrict__ agg, const void* __restrict__ Wp,
    const void* __restrict__ bp, const int* __restrict__ flag,
    void* __restrict__ dout)
{
    const bool f32 = (*flag != 0);
    const int wave = threadIdx.x >> 6, lane = threadIdx.x & 63;
    const int tile = blockIdx.x * 4 + wave;
    const int rb0 = tile & ~15;
    const int o0 = (tile & 15) << 4;
    const int m = lane & 15, qd = lane >> 4;

    const __hip_bfloat16* arow = agg + (size_t)(rb0 + m) * CDIM + qd * 8;
    const size_t bidx = (size_t)(o0 + m) * CDIM + qd * 8;

    floatx4 acc = {0.f, 0.f, 0.f, 0.f};
    #pragma unroll
    for (int k = 0; k < 8; ++k) {
        short8 a = *(const short8*)(arow + k * 32);
        short8 b = ld8bf(Wp, bidx + k * 32, f32);
        acc = __builtin_amdgcn_mfma_f32_16x16x32_bf16(a, b, acc, 0, 0, 0);
    }
    const int o = o0 + (lane & 15);
    const float bv_ = ldf(bp, (size_t)o, f32);
    #pragma unroll
    for (int rg = 0; rg < 4; ++rg) {
        const int rb = rb0 + (lane >> 4) * 4 + rg;
        st_out(dout, (size_t)rb * CDIM + o, acc[rg] + bv_, f32);
    }
}

extern "C" void kernel_launch(void* const* d_in, const int* in_sizes, int n_in,
                              void* d_out, int out_size, void* d_ws, size_t ws_size,
                              hipStream_t stream)
{
    const void* q   = d_in[0];
    const void* k   = d_in[1];
    const void* v   = d_in[2];
    const void* Wq  = d_in[3];
    const void* bq  = d_in[4];
    const void* Wk  = d_in[5];
    const void* bk  = d_in[6];
    const void* Wv  = d_in[7];
    const void* bv  = d_in[8];
    const void* rkw = d_in[9];
    const void* rkb = d_in[10];
    const void* rlv = d_in[11];
    const void* Wp  = d_in[12];
    const void* bp  = d_in[13];

    // ws layout: flag(64B) | relvT(115200B) | qs | ks | vs | agg (PROJ bf16 each) | rel
    char* wsb = (char*)d_ws;
    int* flag = (int*)wsb;
    __hip_bfloat16* relvT = (__hip_bfloat16*)(wsb + 64);
    __hip_bfloat16* qs    = (__hip_bfloat16*)(wsb + 64 + 115200);
    __hip_bfloat16* ks    = qs + PROJ;
    __hip_bfloat16* vs    = ks + PROJ;
    __hip_bfloat16* agg   = vs + PROJ;
    __hip_bfloat16* rel   = agg + PROJ;
    const size_t need = 64 + 115200 + (size_t)4 * PROJ * 2 + (size_t)NB * NHEAD * HW * RELW * 2;
    const bool userel = (ws_size >= need);

    detect_kernel<<<1, 64, 0, stream>>>(q, flag);
    relvT_kernel<<<8, 256, 0, stream>>>(rlv, flag, relvT);
    proj_fused<<<dim3(50, 2, 3), 256, 0, stream>>>(q, k, v, Wq, bq, Wk, bk, Wv, bv,
                                                   flag, qs, ks, vs);
    if (userel) {
        rel_gemm<<<dim3(25, 16), 256, 0, stream>>>(qs, rkw, rkb, flag, rel);
        attn_mfma<<<dim3(120, 16), 256, 0, stream>>>(qs, ks, vs, rel, relvT, flag, agg, d_out);
    } else {
        attn_kernel<0><<<6400, 256, 0, stream>>>(qs, ks, vs, rel, relvT, rkw, rkb, flag, agg, d_out);
    }
    out_mfma<<<800, 256, 0, stream>>>(agg, Wp, bp, flag, d_out);
}

// Round 7
// 183.754 us; speedup vs baseline: 3.5177x; 1.1309x over previous
//
#include <hip/hip_runtime.h>
#include <hip/hip_bf16.h>

#define HW    1600
#define NB    2
#define NHEAD 8
#define HD    32
#define WS2   225
#define WDIM  40
#define CDIM  256
#define PROJ  819200                 // NB*NHEAD*HW*HD elements
#define RELW  240                    // padded w-stride of rel buffer (global)
#define RELSTR 248                   // LDS rel row stride (multiple of 8 shorts = 16B!)
#define TSC   5.656854249492381f     // sqrt(32)

typedef __attribute__((ext_vector_type(8))) short short8;
typedef __attribute__((ext_vector_type(4))) float floatx4;

static __device__ __forceinline__ float bu2f(short u) {
    return __uint_as_float(((unsigned)(unsigned short)u) << 16);
}
static __device__ __forceinline__ short f2bu(float f) {
    __hip_bfloat16 h = __float2bfloat16(f);
    short s; __builtin_memcpy(&s, &h, 2); return s;
}
static __device__ __forceinline__ unsigned pk2(short a, short b) {
    return (unsigned)(unsigned short)a | ((unsigned)(unsigned short)b << 16);
}
static __device__ __forceinline__ float ldf(const void* p, size_t i, bool f32) {
    return f32 ? ((const float*)p)[i] : __bfloat162float(((const __hip_bfloat16*)p)[i]);
}
static __device__ __forceinline__ void st_out(void* p, size_t i, float v, bool f32) {
    if (f32) ((float*)p)[i] = v;
    else     ((__hip_bfloat16*)p)[i] = __float2bfloat16(v);
}
static __device__ __forceinline__ short8 ld8bf(const void* p, size_t i, bool f32) {
    if (!f32) return *(const short8*)((const __hip_bfloat16*)p + i);
    const float* f = (const float*)p + i;
    short8 r;
    #pragma unroll
    for (int t = 0; t < 8; ++t) r[t] = f2bu(f[t]);
    return r;
}
static __device__ __forceinline__ void ld8f(const void* p, size_t i, bool f32, float* o) {
    if (f32) {
        const float* f = (const float*)p + i;
        #pragma unroll
        for (int t = 0; t < 8; ++t) o[t] = f[t];
    } else {
        short8 s = *(const short8*)((const __hip_bfloat16*)p + i);
        #pragma unroll
        for (int t = 0; t < 8; ++t) o[t] = bu2f(s[t]);
    }
}

// ---------------- Kernel 0: input dtype detection ----------------
__global__ __launch_bounds__(64) void detect_kernel(const void* qv, int* flag) {
    const __hip_bfloat16* qb = (const __hip_bfloat16*)qv;
    int bad = 0;
    for (int i = threadIdx.x; i < 4096; i += 64) {
        float v = __bfloat162float(qb[i]);
        if (!(v > -1e6f && v < 1e6f)) bad = 1;
    }
    bad = (__any(bad) ? 1 : 0);
    if (threadIdx.x == 0) *flag = bad;
}

// ---------------- Kernel 1: relv [h][d][w] -> relvT [h][w][d] bf16 ----------------
__global__ __launch_bounds__(256) void relvT_kernel(const void* __restrict__ relv,
                                                    const int* __restrict__ flag,
                                                    __hip_bfloat16* __restrict__ relvT) {
    const bool f32 = (*flag != 0);
    const int h = blockIdx.x;
    for (int idx = threadIdx.x; idx < WS2 * HD; idx += 256) {
        const int w = idx >> 5, d = idx & 31;
        relvT[(size_t)h * WS2 * HD + idx] =
            __float2bfloat16(ldf(relv, ((size_t)h * HD + d) * WS2 + w, f32));
    }
}

// ---------------- Kernel 2: fused transpose + projection GEMM (q,k,v) -------------
__global__ __launch_bounds__(256) void proj_fused(
    const void* __restrict__ xq, const void* __restrict__ xk, const void* __restrict__ xv,
    const void* __restrict__ Wq, const void* __restrict__ bq,
    const void* __restrict__ Wk, const void* __restrict__ bk,
    const void* __restrict__ Wv, const void* __restrict__ bv,
    const int* __restrict__ flag,
    __hip_bfloat16* __restrict__ qs, __hip_bfloat16* __restrict__ ks,
    __hip_bfloat16* __restrict__ vs)
{
    __shared__ short xt[32][264];
    const bool f32 = (*flag != 0);
    const int m0 = blockIdx.x * 32;
    const int n  = blockIdx.y;
    const int t  = blockIdx.z;
    const void *x, *W, *bias; __hip_bfloat16* dst; float scale;
    if (t == 0)      { x = xq; W = Wq; bias = bq; dst = qs; scale = 0.17677669529663687f; }
    else if (t == 1) { x = xk; W = Wk; bias = bk; dst = ks; scale = 1.f; }
    else             { x = xv; W = Wv; bias = bv; dst = vs; scale = 1.f; }

    {
        const int c = threadIdx.x;
        const size_t xb = ((size_t)n * CDIM + c) * HW + m0;
        if (f32) {
            const float* xr = (const float*)x + xb;
            #pragma unroll
            for (int g = 0; g < 8; ++g) {
                float4 f = *(const float4*)(xr + g * 4);
                xt[g*4+0][c] = f2bu(f.x); xt[g*4+1][c] = f2bu(f.y);
                xt[g*4+2][c] = f2bu(f.z); xt[g*4+3][c] = f2bu(f.w);
            }
        } else {
            const __hip_bfloat16* xr = (const __hip_bfloat16*)x + xb;
            #pragma unroll
            for (int g = 0; g < 4; ++g) {
                short8 s = *(const short8*)(xr + g * 8);
                #pragma unroll
                for (int u = 0; u < 8; ++u) xt[g*8+u][c] = s[u];
            }
        }
    }
    __syncthreads();

    const int wave = threadIdx.x >> 6, lane = threadIdx.x & 63;
    const int m = lane & 15, qd = lane >> 4;

    short8 A[2][8];
    #pragma unroll
    for (int mt = 0; mt < 2; ++mt)
        #pragma unroll
        for (int k = 0; k < 8; ++k)
            A[mt][k] = *(const short8*)(&xt[mt*16 + m][k*32 + qd*8]);

    #pragma unroll
    for (int og = 0; og < 4; ++og) {
        const int o0 = (wave * 4 + og) * 16;
        short8 B[8];
        #pragma unroll
        for (int k = 0; k < 8; ++k)
            B[k] = ld8bf(W, (size_t)(o0 + m) * CDIM + k*32 + qd*8, f32);
        floatx4 acc0 = {0,0,0,0}, acc1 = {0,0,0,0};
        #pragma unroll
        for (int k = 0; k < 8; ++k) {
            acc0 = __builtin_amdgcn_mfma_f32_16x16x32_bf16(A[0][k], B[k], acc0, 0, 0, 0);
            acc1 = __builtin_amdgcn_mfma_f32_16x16x32_bf16(A[1][k], B[k], acc1, 0, 0, 0);
        }
        const int o = o0 + (lane & 15), h = o >> 5, d = o & 31;
        const float bv_ = ldf(bias, (size_t)o, f32);
        #pragma unroll
        for (int rg = 0; rg < 4; ++rg) {
            const int p = m0 + (lane >> 4) * 4 + rg;
            dst[((size_t)(n*NHEAD + h)*HW + p)*HD + d]      = __float2bfloat16((acc0[rg] + bv_) * scale);
            dst[((size_t)(n*NHEAD + h)*HW + p + 16)*HD + d] = __float2bfloat16((acc1[rg] + bv_) * scale);
        }
    }
}

// ---------------- Kernel 3: rel GEMM via MFMA ----------------
__global__ __launch_bounds__(256) void rel_gemm(
    const __hip_bfloat16* __restrict__ qs, const void* __restrict__ rkw,
    const void* __restrict__ rkb, const int* __restrict__ flag,
    __hip_bfloat16* __restrict__ rel)
{
    const bool f32 = (*flag != 0);
    const int wave = threadIdx.x >> 6, lane = threadIdx.x & 63;
    const int i0 = blockIdx.x * 64;
    const int nh_ = blockIdx.y;
    const int h = nh_ & 7;
    const int m = lane & 15, qd = lane >> 4;

    short8 A[4];
    #pragma unroll
    for (int it = 0; it < 4; ++it)
        A[it] = *(const short8*)(qs + ((size_t)nh_ * HW + i0 + it*16 + m) * HD + qd*8);

    for (int wt = wave; wt < 15; wt += 4) {
        const int w0 = wt * 16;
        const int wl = min(w0 + m, WS2 - 1);
        short8 B = ld8bf(rkw, ((size_t)h * WS2 + wl) * HD + qd*8, f32);
        const int wcol = w0 + (lane & 15);
        const float rb_ = (wcol < WS2) ? ldf(rkb, (size_t)h * WS2 + wcol, f32) : 0.f;
        #pragma unroll
        for (int it = 0; it < 4; ++it) {
            floatx4 acc = {0,0,0,0};
            acc = __builtin_amdgcn_mfma_f32_16x16x32_bf16(A[it], B, acc, 0, 0, 0);
            if (wcol < WS2) {
                #pragma unroll
                for (int rg = 0; rg < 4; ++rg) {
                    const int i = i0 + it*16 + (lane >> 4)*4 + rg;
                    rel[((size_t)nh_ * HW + i) * RELW + wcol] =
                        __float2bfloat16(acc[rg] * TSC + rb_);
                }
            }
        }
    }
}

// ---------------- Kernel 4: full-MFMA fused local attention ----------------
// LDS regions (time-multiplexed, 39.2 KB):
//   sP  [16][488] u16 : kk-space P                        (15,616 B)
//   R2: sRel [16][248] u16 -> then sPw [16][264] u16      (8,448 B)
//   R1: V^T [16][488] u16 -> Rv^T [16][264] u16 -> sOh f32[1024]  (15,616 B)
#define SP_OFF    0
#define R2_OFF    15616
#define R1_OFF    24064
#define SMAX_OFF  39680
#define SSUM_OFF  39936
#define SMEM_SZ   40192

__global__ __launch_bounds__(256) void attn_mfma(
    const __hip_bfloat16* __restrict__ qs, const __hip_bfloat16* __restrict__ ks,
    const __hip_bfloat16* __restrict__ vs,
    const __hip_bfloat16* __restrict__ rel,     // [nh*1600, 240]
    const __hip_bfloat16* __restrict__ relvT,   // [h][w][d]
    const int* __restrict__ flag,
    __hip_bfloat16* __restrict__ agg,           // [hw, n, 256]
    void* __restrict__ dout)
{
    __shared__ __align__(16) char smem[SMEM_SZ];
    short* sP   = (short*)(smem + SP_OFF);
    short* sRel = (short*)(smem + R2_OFF);   // alias: dead before sPw writes
    short* sPw  = (short*)(smem + R2_OFF);
    short* sB   = (short*)(smem + R1_OFF);   // V^T / Rv^T
    float* sOh  = (float*)(smem + R1_OFF);   // O partials (after MFMA reads)
    float* sMax = (float*)(smem + SMAX_OFF);
    float* sSum = (float*)(smem + SSUM_OFF);

    const bool f32 = (*flag != 0);
    const int tid = threadIdx.x;
    const int wave = tid >> 6, lane = tid & 63;
    const int m = lane & 15, quad = lane >> 4;
    const int y = blockIdx.x / 3, tile3 = blockIdx.x % 3;
    const int x0 = (tile3 == 0) ? 0 : (tile3 == 1) ? 16 : 24;
    const int wlo = (tile3 == 2) ? 8 : 0;
    const int nh_ = blockIdx.y;
    const int h = nh_ & 7, n = nh_ >> 3;
    const size_t qb = (size_t)nh_ * HW;
    const size_t qrow0 = qb + (size_t)y * WDIM + x0;

    // ---- stage rel rows for the 16 queries (b128, LDS stride 248 = 16B-aligned) ----
    for (int idx = tid; idx < 480; idx += 256) {
        const int row = idx / 30, c8 = (idx - row * 30) * 8;
        short8 v = *(const short8*)((const short*)rel + (qrow0 + row) * RELW + c8);
        *(short8*)(sRel + row * RELSTR + c8) = v;
    }
    const short8 afrag = *(const short8*)((const short*)qs + (qrow0 + m) * HD + quad * 8);
    __syncthreads();

    // ---- S = Q.K^T + rel ----
    float L[8][4];
    #pragma unroll
    for (int j = 0; j < 8; ++j)
        #pragma unroll
        for (int rg = 0; rg < 4; ++rg) L[j][rg] = -1e30f;

    #pragma unroll
    for (int j = 0; j < 8; ++j) {
        const int t = wave + 4 * j;
        if (t < 30) {
            const int r = t >> 1, c0_ = (t & 1) << 4;
            const int cc = c0_ + m;                 // key col 0..31
            const int ky = y + r - 7, kx = x0 - 7 + cc;
            const int gky = min(max(ky, 0), WDIM - 1), gkx = min(max(kx, 0), WDIM - 1);
            const short8 bfrag = *(const short8*)((const short*)ks + (qb + (size_t)gky * WDIM + gkx) * HD + quad * 8);
            floatx4 s4 = {0.f, 0.f, 0.f, 0.f};
            s4 = __builtin_amdgcn_mfma_f32_16x16x32_bf16(afrag, bfrag, s4, 0, 0, 0);
            const bool inimg = ((unsigned)ky < (unsigned)WDIM) && ((unsigned)kx < (unsigned)WDIM);
            #pragma unroll
            for (int rg = 0; rg < 4; ++rg) {
                const int qm = quad * 4 + rg;
                const int dx7 = cc - qm;
                if (inimg && (unsigned)dx7 < 15u)
                    L[j][rg] = s4[rg] + bu2f(sRel[qm * RELSTR + r * 15 + dx7]);
            }
        }
    }

    // ---- block softmax per query row ----
    float mx[4];
    #pragma unroll
    for (int rg = 0; rg < 4; ++rg) {
        mx[rg] = L[0][rg];
        #pragma unroll
        for (int j = 1; j < 8; ++j) mx[rg] = fmaxf(mx[rg], L[j][rg]);
        #pragma unroll
        for (int off = 1; off <= 8; off <<= 1) mx[rg] = fmaxf(mx[rg], __shfl_xor(mx[rg], off));
    }
    if (m == 0) {
        #pragma unroll
        for (int rg = 0; rg < 4; ++rg) sMax[(quad * 4 + rg) * 4 + wave] = mx[rg];
    }
    __syncthreads();
    float M4[4], sm[4];
    #pragma unroll
    for (int rg = 0; rg < 4; ++rg) {
        const float4 v = *(const float4*)&sMax[(quad * 4 + rg) * 4];
        M4[rg] = fmaxf(fmaxf(v.x, v.y), fmaxf(v.z, v.w));
        sm[rg] = 0.f;
    }
    #pragma unroll
    for (int j = 0; j < 8; ++j)
        #pragma unroll
        for (int rg = 0; rg < 4; ++rg) { L[j][rg] = expf(L[j][rg] - M4[rg]); sm[rg] += L[j][rg]; }
    #pragma unroll
    for (int rg = 0; rg < 4; ++rg)
        #pragma unroll
        for (int off = 1; off <= 8; off <<= 1) sm[rg] += __shfl_xor(sm[rg], off);
    if (m == 0) {
        #pragma unroll
        for (int rg = 0; rg < 4; ++rg) sSum[(quad * 4 + rg) * 4 + wave] = sm[rg];
    }
    __syncthreads();
    float inv4[4];
    #pragma unroll
    for (int rg = 0; rg < 4; ++rg) {
        const float4 v = *(const float4*)&sSum[(quad * 4 + rg) * 4];
        inv4[rg] = 1.f / (v.x + v.y + v.z + v.w);
    }

    // ---- zero sPw pad cols 225..263 (sRel alias dead: all reads preceded the
    //      first softmax barrier). MFMA A-operand reads cols up to 255; leftover
    //      LDS garbage there could be Inf/NaN and 0*Inf = NaN. ----
    for (int e = tid; e < 16 * 39; e += 256) {
        const int row = e / 39, c = 225 + (e - row * 39);
        sPw[row * 264 + c] = 0;
    }

    // ---- write P: kk-space (full) + w-space (all 225 slots; 0 for out-of-image) ----
    #pragma unroll
    for (int j = 0; j < 8; ++j) {
        const int t = wave + 4 * j;
        if (t < 30) {
            const int r = t >> 1, cc = ((t & 1) << 4) + m;
            #pragma unroll
            for (int rg = 0; rg < 4; ++rg) {
                const int qm = quad * 4 + rg;
                const short pb = f2bu(L[j][rg] * inv4[rg]);   // exact 0 when invalid
                sP[qm * 488 + r * 32 + cc] = pb;
                const int dx7 = cc - qm;
                if ((unsigned)dx7 < 15u) sPw[qm * 264 + r * 15 + dx7] = pb;
            }
        }
    }
    __syncthreads();

    // ---- coalesced attn_out copy from w-space P ----
    #pragma unroll
    for (int rr = 0; rr < 4; ++rr) {
        const int qm = wave * 4 + rr;
        if (qm >= wlo) {
            const size_t obase = (size_t)PROJ + (qrow0 + qm) * WS2;
            #pragma unroll
            for (int c = 0; c < 4; ++c) {
                const int col = lane + 64 * c;
                if (col < WS2) st_out(dout, obase + col, bu2f(sPw[qm * 264 + col]), f32);
            }
        }
    }

    // ---- PV + rel_v GEMMs, d in halves of 16; R1 = V^T -> Rv^T -> sOh ----
    for (int half = 0; half < 2; ++half) {
        __syncthreads();
        const int h16 = half << 4;
        {   // stage V^T rows [d-half][kk], packed u32 pairs, stride 488 shorts
            unsigned* dstw = (unsigned*)sB;
            for (int p = tid; p < 240; p += 256) {
                const int kk0 = 2 * p;
                const int r = kk0 >> 5, c = kk0 & 31;
                const int gky = min(max(y + r - 7, 0), WDIM - 1);
                const int gkx0 = min(max(x0 - 7 + c, 0), WDIM - 1);
                const int gkx1 = min(max(x0 - 7 + c + 1, 0), WDIM - 1);
                const short* v0 = (const short*)vs + (qb + (size_t)gky * WDIM + gkx0) * HD + h16;
                const short* v1 = (const short*)vs + (qb + (size_t)gky * WDIM + gkx1) * HD + h16;
                const short8 a0 = *(const short8*)v0, b0 = *(const short8*)v1;
                const short8 a1 = *(const short8*)(v0 + 8), b1 = *(const short8*)(v1 + 8);
                #pragma unroll
                for (int dd = 0; dd < 8; ++dd) dstw[dd * 244 + p] = pk2(a0[dd], b0[dd]);
                #pragma unroll
                for (int dd = 0; dd < 8; ++dd) dstw[(dd + 8) * 244 + p] = pk2(a1[dd], b1[dd]);
            }
        }
        __syncthreads();
        floatx4 acc = {0.f, 0.f, 0.f, 0.f};
        for (int u = wave; u < 15; u += 4) {
            const short8 Af = *(const short8*)(sP + m * 488 + u * 32 + quad * 8);
            const short8 Bf = *(const short8*)(sB + m * 488 + u * 32 + quad * 8);
            acc = __builtin_amdgcn_mfma_f32_16x16x32_bf16(Af, Bf, acc, 0, 0, 0);
        }
        __syncthreads();
        {   // stage Rv^T rows [d-half][w], stride 264 shorts, zeros for w>=225
            unsigned* dstw = (unsigned*)sB;
            for (int p = tid; p < 132; p += 256) {
                const int w0 = 2 * p;
                short8 a0 = {0,0,0,0,0,0,0,0}, a1 = a0, b0 = a0, b1 = a0;
                if (w0 < WS2) {
                    const short* rp = (const short*)relvT + ((size_t)h * WS2 + w0) * HD + h16;
                    a0 = *(const short8*)rp; a1 = *(const short8*)(rp + 8);
                }
                if (w0 + 1 < WS2) {
                    const short* rp = (const short*)relvT + ((size_t)h * WS2 + w0 + 1) * HD + h16;
                    b0 = *(const short8*)rp; b1 = *(const short8*)(rp + 8);
                }
                #pragma unroll
                for (int dd = 0; dd < 8; ++dd) dstw[dd * 132 + p] = pk2(a0[dd], b0[dd]);
                #pragma unroll
                for (int dd = 0; dd < 8; ++dd) dstw[(dd + 8) * 132 + p] = pk2(a1[dd], b1[dd]);
            }
        }
        __syncthreads();
        for (int u = wave; u < 8; u += 4) {
            const short8 Af = *(const short8*)(sPw + m * 264 + u * 32 + quad * 8);
            const short8 Bf = *(const short8*)(sB + m * 264 + u * 32 + quad * 8);
            acc = __builtin_amdgcn_mfma_f32_16x16x32_bf16(Af, Bf, acc, 0, 0, 0);
        }
        __syncthreads();
        #pragma unroll
        for (int rg = 0; rg < 4; ++rg)
            sOh[wave * 256 + (quad * 4 + rg) * 16 + m] = acc[rg];
        __syncthreads();
        {
            const int qq = tid >> 4, dd = tid & 15;
            const float s = sOh[tid] + sOh[256 + tid] + sOh[512 + tid] + sOh[768 + tid];
            if (qq >= wlo) {
                const size_t i = (size_t)y * WDIM + x0 + qq;
                agg[(i * NB + n) * CDIM + h * HD + h16 + dd] = __float2bfloat16(s);
            }
        }
    }
}

// ---------------- Kernel 4b: fallback scalar attention (ws too small) ------
__global__ __launch_bounds__(256) void attn_fallback(
    const __hip_bfloat16* __restrict__ qs, const __hip_bfloat16* __restrict__ ks,
    const __hip_bfloat16* __restrict__ vs,
    const __hip_bfloat16* __restrict__ relvT,
    const void* __restrict__ rkw, const void* __restrict__ rkb,
    const int* __restrict__ flag,
    __hip_bfloat16* __restrict__ agg,
    void* __restrict__ dout)
{
    __shared__ float sL[4][240];

    const bool f32 = (*flag != 0);
    const int wave = threadIdx.x >> 6, lane = threadIdx.x & 63;
    const int qidx = blockIdx.x * 4 + wave;
    const int i = qidx % HW, nh_ = qidx / HW;
    const int h = nh_ & (NHEAD - 1), n = nh_ >> 3;
    const int y = i / WDIM, x = i - y * WDIM;

    const int w16 = lane >> 2, qq = lane & 3;
    float q8[8];
    {
        short8 qv = *(const short8*)(qs + (size_t)qidx * HD + qq * 8);
        #pragma unroll
        for (int t = 0; t < 8; ++t) q8[t] = bu2f(qv[t]);
    }

    const int kxu = x + w16 - 7;
    const bool vw = (w16 < 15);
    for (int r = 0; r < 15; ++r) {
        const int ky = y + r - 7;
        const int widx = r * 15 + w16;
        const bool vimg = vw && ((unsigned)ky < WDIM) && ((unsigned)kxu < WDIM);
        float part = 0.f;
        if (vimg) {
            short8 kv = *(const short8*)(ks + ((size_t)nh_ * HW + ky * WDIM + kxu) * HD + qq * 8);
            float r8[8];
            ld8f(rkw, ((size_t)h * WS2 + widx) * HD + qq * 8, f32, r8);
            #pragma unroll
            for (int t = 0; t < 8; ++t) part += q8[t] * (bu2f(kv[t]) + TSC * r8[t]);
        }
        part += __shfl_xor(part, 1);
        part += __shfl_xor(part, 2);
        if (qq == 0) {
            float lg = -1e30f;
            if (vimg) lg = part + ldf(rkb, (size_t)h * WS2 + widx, f32);
            sL[wave][vw ? widx : (225 + r)] = lg;
        }
    }

    float lg[4];
    float mx = -1e30f;
    #pragma unroll
    for (int c = 0; c < 4; ++c) {
        const int w_ = lane + 64 * c;
        lg[c] = (w_ < 240) ? sL[wave][w_] : -1e30f;
        mx = fmaxf(mx, lg[c]);
    }
    #pragma unroll
    for (int off = 32; off > 0; off >>= 1) mx = fmaxf(mx, __shfl_xor(mx, off));
    float s = 0.f;
    #pragma unroll
    for (int c = 0; c < 4; ++c) { lg[c] = expf(lg[c] - mx); s += lg[c]; }
    #pragma unroll
    for (int off = 32; off > 0; off >>= 1) s += __shfl_xor(s, off);
    const float inv = (s > 0.f) ? (1.0f / s) : 0.f;
    #pragma unroll
    for (int c = 0; c < 4; ++c) {
        const int w_ = lane + 64 * c;
        if (w_ < WS2) {
            const float a = lg[c] * inv;
            sL[wave][w_] = a;
            st_out(dout, (size_t)PROJ + (size_t)qidx * WS2 + w_, a, f32);
        }
    }

    float o8[8] = {0.f, 0.f, 0.f, 0.f, 0.f, 0.f, 0.f, 0.f};
    if (vw) {
        for (int r = 0; r < 15; ++r) {
            const int widx = r * 15 + w16;
            const int kyc = min(max(y + r - 7, 0), WDIM - 1);
            const int kxc = min(max(kxu, 0), WDIM - 1);
            const float P = sL[wave][widx];
            short8 vv = *(const short8*)(vs + ((size_t)nh_ * HW + kyc * WDIM + kxc) * HD + qq * 8);
            short8 rv = *(const short8*)(relvT + ((size_t)h * WS2 + widx) * HD + qq * 8);
            #pragma unroll
            for (int t = 0; t < 8; ++t) o8[t] += P * (bu2f(vv[t]) + bu2f(rv[t]));
        }
    }
    #pragma unroll
    for (int off = 4; off <= 32; off <<= 1)
        #pragma unroll
        for (int t = 0; t < 8; ++t) o8[t] += __shfl_xor(o8[t], off);
    if (lane < 4) {
        short8 tmp;
        #pragma unroll
        for (int t = 0; t < 8; ++t) tmp[t] = f2bu(o8[t]);
        *(short8*)(agg + ((size_t)i * NB + n) * CDIM + h * HD + qq * 8) = tmp;
    }
}

// ---------------- Kernel 5: output projection via MFMA ----------------
__global__ __launch_bounds__(256) void out_mfma(
    const __hip_bfloat16* __restrict__ agg, const void* __restrict__ Wp,
    const void* __restrict__ bp, const int* __restrict__ flag,
    void* __restrict__ dout)
{
    const bool f32 = (*flag != 0);
    const int wave = threadIdx.x >> 6, lane = threadIdx.x & 63;
    const int tile = blockIdx.x * 4 + wave;
    const int rb0 = tile & ~15;
    const int o0 = (tile & 15) << 4;
    const int m = lane & 15, qd = lane >> 4;

    const __hip_bfloat16* arow = agg + (size_t)(rb0 + m) * CDIM + qd * 8;
    const size_t bidx = (size_t)(o0 + m) * CDIM + qd * 8;

    floatx4 acc = {0.f, 0.f, 0.f, 0.f};
    #pragma unroll
    for (int k = 0; k < 8; ++k) {
        short8 a = *(const short8*)(arow + k * 32);
        short8 b = ld8bf(Wp, bidx + k * 32, f32);
        acc = __builtin_amdgcn_mfma_f32_16x16x32_bf16(a, b, acc, 0, 0, 0);
    }
    const int o = o0 + (lane & 15);
    const float bv_ = ldf(bp, (size_t)o, f32);
    #pragma unroll
    for (int rg = 0; rg < 4; ++rg) {
        const int rb = rb0 + (lane >> 4) * 4 + rg;
        st_out(dout, (size_t)rb * CDIM + o, acc[rg] + bv_, f32);
    }
}

extern "C" void kernel_launch(void* const* d_in, const int* in_sizes, int n_in,
                              void* d_out, int out_size, void* d_ws, size_t ws_size,
                              hipStream_t stream)
{
    const void* q   = d_in[0];
    const void* k   = d_in[1];
    const void* v   = d_in[2];
    const void* Wq  = d_in[3];
    const void* bq  = d_in[4];
    const void* Wk  = d_in[5];
    const void* bk  = d_in[6];
    const void* Wv  = d_in[7];
    const void* bv  = d_in[8];
    const void* rkw = d_in[9];
    const void* rkb = d_in[10];
    const void* rlv = d_in[11];
    const void* Wp  = d_in[12];
    const void* bp  = d_in[13];

    // ws layout: flag(64B) | relvT(115200B) | qs | ks | vs | agg (PROJ bf16 each) | rel
    char* wsb = (char*)d_ws;
    int* flag = (int*)wsb;
    __hip_bfloat16* relvT = (__hip_bfloat16*)(wsb + 64);
    __hip_bfloat16* qs    = (__hip_bfloat16*)(wsb + 64 + 115200);
    __hip_bfloat16* ks    = qs + PROJ;
    __hip_bfloat16* vs    = ks + PROJ;
    __hip_bfloat16* agg   = vs + PROJ;
    __hip_bfloat16* rel   = agg + PROJ;
    const size_t need = 64 + 115200 + (size_t)4 * PROJ * 2 + (size_t)NB * NHEAD * HW * RELW * 2;
    const bool userel = (ws_size >= need);

    detect_kernel<<<1, 64, 0, stream>>>(q, flag);
    relvT_kernel<<<8, 256, 0, stream>>>(rlv, flag, relvT);
    proj_fused<<<dim3(50, 2, 3), 256, 0, stream>>>(q, k, v, Wq, bq, Wk, bk, Wv, bv,
                                                   flag, qs, ks, vs);
    if (userel) {
        rel_gemm<<<dim3(25, 16), 256, 0, stream>>>(qs, rkw, rkb, flag, rel);
        attn_mfma<<<dim3(120, 16), 256, 0, stream>>>(qs, ks, vs, rel, relvT, flag, agg, d_out);
    } else {
        attn_fallback<<<6400, 256, 0, stream>>>(qs, ks, vs, relvT, rkw, rkb, flag, agg, d_out);
    }
    out_mfma<<<800, 256, 0, stream>>>(agg, Wp, bp, flag, d_out);
}

// Round 8
// 169.131 us; speedup vs baseline: 3.8219x; 1.0865x over previous
//
#include <hip/hip_runtime.h>
#include <hip/hip_bf16.h>

#define HW    1600
#define NB    2
#define NHEAD 8
#define HD    32
#define WS2   225
#define WDIM  40
#define CDIM  256
#define PROJ  819200                 // NB*NHEAD*HW*HD elements
#define RELSTR 248                   // LDS rel row stride (multiple of 8 shorts = 16B)
#define TSC   5.656854249492381f     // sqrt(32)

typedef __attribute__((ext_vector_type(8))) short short8;
typedef __attribute__((ext_vector_type(4))) float floatx4;

static __device__ __forceinline__ float bu2f(short u) {
    return __uint_as_float(((unsigned)(unsigned short)u) << 16);
}
static __device__ __forceinline__ short f2bu(float f) {
    __hip_bfloat16 h = __float2bfloat16(f);
    short s; __builtin_memcpy(&s, &h, 2); return s;
}
static __device__ __forceinline__ unsigned pk2(short a, short b) {
    return (unsigned)(unsigned short)a | ((unsigned)(unsigned short)b << 16);
}
static __device__ __forceinline__ float ldf(const void* p, size_t i, bool f32) {
    return f32 ? ((const float*)p)[i] : __bfloat162float(((const __hip_bfloat16*)p)[i]);
}
static __device__ __forceinline__ void st_out(void* p, size_t i, float v, bool f32) {
    if (f32) ((float*)p)[i] = v;
    else     ((__hip_bfloat16*)p)[i] = __float2bfloat16(v);
}
static __device__ __forceinline__ short8 ld8bf(const void* p, size_t i, bool f32) {
    if (!f32) return *(const short8*)((const __hip_bfloat16*)p + i);
    const float* f = (const float*)p + i;
    short8 r;
    #pragma unroll
    for (int t = 0; t < 8; ++t) r[t] = f2bu(f[t]);
    return r;
}

// ---------------- Kernel 1: prep = dtype detect + relv transpose ----------------
// grid 8 (one block per head). Each block computes its own dtype flag from q
// (redundant but cheap, avoids a cross-block dependency); block 0 publishes it.
__global__ __launch_bounds__(256) void prep_kernel(const void* __restrict__ q,
                                                   const void* __restrict__ relv,
                                                   int* __restrict__ flag,
                                                   __hip_bfloat16* __restrict__ relvT) {
    __shared__ int sbad;
    if (threadIdx.x == 0) sbad = 0;
    __syncthreads();
    int bad = 0;
    const __hip_bfloat16* qb = (const __hip_bfloat16*)q;
    for (int i = threadIdx.x; i < 4096; i += 256) {
        float v = __bfloat162float(qb[i]);
        if (!(v > -1e6f && v < 1e6f)) bad = 1;   // fp32-misread garbage / NaN
    }
    if (bad) sbad = 1;
    __syncthreads();
    const bool f32 = (sbad != 0);
    if (blockIdx.x == 0 && threadIdx.x == 0) *flag = sbad;
    const int h = blockIdx.x;
    for (int idx = threadIdx.x; idx < WS2 * HD; idx += 256) {
        const int w = idx >> 5, d = idx & 31;
        relvT[(size_t)h * WS2 * HD + idx] =
            __float2bfloat16(ldf(relv, ((size_t)h * HD + d) * WS2 + w, f32));
    }
}

// ---------------- Kernel 2: fused transpose + projection GEMM (q,k,v) -------------
__global__ __launch_bounds__(256) void proj_fused(
    const void* __restrict__ xq, const void* __restrict__ xk, const void* __restrict__ xv,
    const void* __restrict__ Wq, const void* __restrict__ bq,
    const void* __restrict__ Wk, const void* __restrict__ bk,
    const void* __restrict__ Wv, const void* __restrict__ bv,
    const int* __restrict__ flag,
    __hip_bfloat16* __restrict__ qs, __hip_bfloat16* __restrict__ ks,
    __hip_bfloat16* __restrict__ vs)
{
    __shared__ short xt[32][264];
    const bool f32 = (*flag != 0);
    const int m0 = blockIdx.x * 32;
    const int n  = blockIdx.y;
    const int t  = blockIdx.z;
    const void *x, *W, *bias; __hip_bfloat16* dst; float scale;
    if (t == 0)      { x = xq; W = Wq; bias = bq; dst = qs; scale = 0.17677669529663687f; }
    else if (t == 1) { x = xk; W = Wk; bias = bk; dst = ks; scale = 1.f; }
    else             { x = xv; W = Wv; bias = bv; dst = vs; scale = 1.f; }

    {
        const int c = threadIdx.x;
        const size_t xb = ((size_t)n * CDIM + c) * HW + m0;
        if (f32) {
            const float* xr = (const float*)x + xb;
            #pragma unroll
            for (int g = 0; g < 8; ++g) {
                float4 f = *(const float4*)(xr + g * 4);
                xt[g*4+0][c] = f2bu(f.x); xt[g*4+1][c] = f2bu(f.y);
                xt[g*4+2][c] = f2bu(f.z); xt[g*4+3][c] = f2bu(f.w);
            }
        } else {
            const __hip_bfloat16* xr = (const __hip_bfloat16*)x + xb;
            #pragma unroll
            for (int g = 0; g < 4; ++g) {
                short8 s = *(const short8*)(xr + g * 8);
                #pragma unroll
                for (int u = 0; u < 8; ++u) xt[g*8+u][c] = s[u];
            }
        }
    }
    __syncthreads();

    const int wave = threadIdx.x >> 6, lane = threadIdx.x & 63;
    const int m = lane & 15, qd = lane >> 4;

    short8 A[2][8];
    #pragma unroll
    for (int mt = 0; mt < 2; ++mt)
        #pragma unroll
        for (int k = 0; k < 8; ++k)
            A[mt][k] = *(const short8*)(&xt[mt*16 + m][k*32 + qd*8]);

    #pragma unroll
    for (int og = 0; og < 4; ++og) {
        const int o0 = (wave * 4 + og) * 16;
        short8 B[8];
        #pragma unroll
        for (int k = 0; k < 8; ++k)
            B[k] = ld8bf(W, (size_t)(o0 + m) * CDIM + k*32 + qd*8, f32);
        floatx4 acc0 = {0,0,0,0}, acc1 = {0,0,0,0};
        #pragma unroll
        for (int k = 0; k < 8; ++k) {
            acc0 = __builtin_amdgcn_mfma_f32_16x16x32_bf16(A[0][k], B[k], acc0, 0, 0, 0);
            acc1 = __builtin_amdgcn_mfma_f32_16x16x32_bf16(A[1][k], B[k], acc1, 0, 0, 0);
        }
        const int o = o0 + (lane & 15), h = o >> 5, d = o & 31;
        const float bv_ = ldf(bias, (size_t)o, f32);
        #pragma unroll
        for (int rg = 0; rg < 4; ++rg) {
            const int p = m0 + (lane >> 4) * 4 + rg;
            dst[((size_t)(n*NHEAD + h)*HW + p)*HD + d]      = __float2bfloat16((acc0[rg] + bv_) * scale);
            dst[((size_t)(n*NHEAD + h)*HW + p + 16)*HD + d] = __float2bfloat16((acc1[rg] + bv_) * scale);
        }
    }
}

// ---------------- Kernel 3: full-MFMA fused local attention (rel in-kernel) -------
// LDS regions (time-multiplexed, 40.7 KB -> 4 blocks/CU):
//   sP  [16][488] u16 : kk-space P                        (15,616 B)
//   R2: sRel [16][248] u16 -> then sPw [16][264] u16      (8,448 B)
//   R1: V^T [16][488] u16 -> Rv^T [16][264] u16 -> sOh f32[1024]  (15,616 B)
//   sMax/sSum f32[64] each, sRkb u16[240]
#define SP_OFF    0
#define R2_OFF    15616
#define R1_OFF    24064
#define SMAX_OFF  39680
#define SSUM_OFF  39936
#define SRKB_OFF  40192
#define SMEM_SZ   40672

__global__ __launch_bounds__(256) void attn_mfma(
    const __hip_bfloat16* __restrict__ qs, const __hip_bfloat16* __restrict__ ks,
    const __hip_bfloat16* __restrict__ vs,
    const void* __restrict__ rkw, const void* __restrict__ rkb,
    const __hip_bfloat16* __restrict__ relvT,   // [h][w][d]
    const int* __restrict__ flag,
    __hip_bfloat16* __restrict__ agg,           // [hw, n, 256]
    void* __restrict__ dout)
{
    __shared__ __align__(16) char smem[SMEM_SZ];
    short* sP   = (short*)(smem + SP_OFF);
    short* sRel = (short*)(smem + R2_OFF);   // alias: dead before sPw writes
    short* sPw  = (short*)(smem + R2_OFF);
    short* sB   = (short*)(smem + R1_OFF);   // V^T / Rv^T
    float* sOh  = (float*)(smem + R1_OFF);   // O partials (after MFMA reads)
    float* sMax = (float*)(smem + SMAX_OFF);
    float* sSum = (float*)(smem + SSUM_OFF);
    short* sRkb = (short*)(smem + SRKB_OFF);

    const bool f32 = (*flag != 0);
    const int tid = threadIdx.x;
    const int wave = tid >> 6, lane = tid & 63;
    const int m = lane & 15, quad = lane >> 4;
    const int y = blockIdx.x / 3, tile3 = blockIdx.x % 3;
    const int x0 = (tile3 == 0) ? 0 : (tile3 == 1) ? 16 : 24;
    const int wlo = (tile3 == 2) ? 8 : 0;
    const int nh_ = blockIdx.y;
    const int h = nh_ & 7, n = nh_ >> 3;
    const size_t qb = (size_t)nh_ * HW;
    const size_t qrow0 = qb + (size_t)y * WDIM + x0;

    // ---- stage rkb[h] -> LDS (bf16; same rounding as the old rel buffer) ----
    for (int wv = tid; wv < 240; wv += 256)
        sRkb[wv] = (wv < WS2) ? f2bu(ldf(rkb, (size_t)h * WS2 + wv, f32)) : (short)0;
    const short8 afrag = *(const short8*)((const short*)qs + (qrow0 + m) * HD + quad * 8);
    __syncthreads();

    // ---- rel[qm][w] = T*(qs . rkw) + rkb via 15 MFMAs (w-tiles split across waves) ----
    for (int wt = wave; wt < 15; wt += 4) {
        const int w0 = wt * 16;
        const int wl = min(w0 + m, WS2 - 1);
        short8 B = ld8bf(rkw, ((size_t)h * WS2 + wl) * HD + quad * 8, f32);
        floatx4 acc = {0.f, 0.f, 0.f, 0.f};
        acc = __builtin_amdgcn_mfma_f32_16x16x32_bf16(afrag, B, acc, 0, 0, 0);
        const int wcol = w0 + m;                  // D: col=lane&15, row=quad*4+rg
        if (wcol < WS2) {
            const float rb_ = bu2f(sRkb[wcol]);
            #pragma unroll
            for (int rg = 0; rg < 4; ++rg)
                sRel[(quad * 4 + rg) * RELSTR + wcol] = f2bu(acc[rg] * TSC + rb_);
        }
    }
    __syncthreads();

    // ---- S = Q.K^T + rel ----
    float L[8][4];
    #pragma unroll
    for (int j = 0; j < 8; ++j)
        #pragma unroll
        for (int rg = 0; rg < 4; ++rg) L[j][rg] = -1e30f;

    #pragma unroll
    for (int j = 0; j < 8; ++j) {
        const int t = wave + 4 * j;
        if (t < 30) {
            const int r = t >> 1, c0_ = (t & 1) << 4;
            const int cc = c0_ + m;                 // key col 0..31
            const int ky = y + r - 7, kx = x0 - 7 + cc;
            const int gky = min(max(ky, 0), WDIM - 1), gkx = min(max(kx, 0), WDIM - 1);
            const short8 bfrag = *(const short8*)((const short*)ks + (qb + (size_t)gky * WDIM + gkx) * HD + quad * 8);
            floatx4 s4 = {0.f, 0.f, 0.f, 0.f};
            s4 = __builtin_amdgcn_mfma_f32_16x16x32_bf16(afrag, bfrag, s4, 0, 0, 0);
            const bool inimg = ((unsigned)ky < (unsigned)WDIM) && ((unsigned)kx < (unsigned)WDIM);
            #pragma unroll
            for (int rg = 0; rg < 4; ++rg) {
                const int qm = quad * 4 + rg;
                const int dx7 = cc - qm;
                if (inimg && (unsigned)dx7 < 15u)
                    L[j][rg] = s4[rg] + bu2f(sRel[qm * RELSTR + r * 15 + dx7]);
            }
        }
    }

    // ---- block softmax per query row ----
    float mx[4];
    #pragma unroll
    for (int rg = 0; rg < 4; ++rg) {
        mx[rg] = L[0][rg];
        #pragma unroll
        for (int j = 1; j < 8; ++j) mx[rg] = fmaxf(mx[rg], L[j][rg]);
        #pragma unroll
        for (int off = 1; off <= 8; off <<= 1) mx[rg] = fmaxf(mx[rg], __shfl_xor(mx[rg], off));
    }
    if (m == 0) {
        #pragma unroll
        for (int rg = 0; rg < 4; ++rg) sMax[(quad * 4 + rg) * 4 + wave] = mx[rg];
    }
    __syncthreads();
    float M4[4], sm[4];
    #pragma unroll
    for (int rg = 0; rg < 4; ++rg) {
        const float4 v = *(const float4*)&sMax[(quad * 4 + rg) * 4];
        M4[rg] = fmaxf(fmaxf(v.x, v.y), fmaxf(v.z, v.w));
        sm[rg] = 0.f;
    }
    #pragma unroll
    for (int j = 0; j < 8; ++j)
        #pragma unroll
        for (int rg = 0; rg < 4; ++rg) { L[j][rg] = expf(L[j][rg] - M4[rg]); sm[rg] += L[j][rg]; }
    #pragma unroll
    for (int rg = 0; rg < 4; ++rg)
        #pragma unroll
        for (int off = 1; off <= 8; off <<= 1) sm[rg] += __shfl_xor(sm[rg], off);
    if (m == 0) {
        #pragma unroll
        for (int rg = 0; rg < 4; ++rg) sSum[(quad * 4 + rg) * 4 + wave] = sm[rg];
    }
    __syncthreads();
    float inv4[4];
    #pragma unroll
    for (int rg = 0; rg < 4; ++rg) {
        const float4 v = *(const float4*)&sSum[(quad * 4 + rg) * 4];
        inv4[rg] = 1.f / (v.x + v.y + v.z + v.w);
    }

    // ---- zero sPw pad cols 225..263 (sRel alias dead: all reads precede this
    //      point via the softmax barriers). MFMA A-operand reads cols up to 255. ----
    for (int e = tid; e < 16 * 39; e += 256) {
        const int row = e / 39, c = 225 + (e - row * 39);
        sPw[row * 264 + c] = 0;
    }

    // ---- write P: kk-space (full) + w-space (all 225 slots; 0 for out-of-image) ----
    #pragma unroll
    for (int j = 0; j < 8; ++j) {
        const int t = wave + 4 * j;
        if (t < 30) {
            const int r = t >> 1, cc = ((t & 1) << 4) + m;
            #pragma unroll
            for (int rg = 0; rg < 4; ++rg) {
                const int qm = quad * 4 + rg;
                const short pb = f2bu(L[j][rg] * inv4[rg]);   // exact 0 when invalid
                sP[qm * 488 + r * 32 + cc] = pb;
                const int dx7 = cc - qm;
                if ((unsigned)dx7 < 15u) sPw[qm * 264 + r * 15 + dx7] = pb;
            }
        }
    }
    __syncthreads();

    // ---- coalesced attn_out copy from w-space P ----
    #pragma unroll
    for (int rr = 0; rr < 4; ++rr) {
        const int qm = wave * 4 + rr;
        if (qm >= wlo) {
            const size_t obase = (size_t)PROJ + (qrow0 + qm) * WS2;
            #pragma unroll
            for (int c = 0; c < 4; ++c) {
                const int col = lane + 64 * c;
                if (col < WS2) st_out(dout, obase + col, bu2f(sPw[qm * 264 + col]), f32);
            }
        }
    }

    // ---- PV + rel_v GEMMs, d in halves of 16; R1 = V^T -> Rv^T -> sOh ----
    for (int half = 0; half < 2; ++half) {
        __syncthreads();
        const int h16 = half << 4;
        {   // stage V^T rows [d-half][kk], packed u32 pairs, stride 488 shorts
            unsigned* dstw = (unsigned*)sB;
            for (int p = tid; p < 240; p += 256) {
                const int kk0 = 2 * p;
                const int r = kk0 >> 5, c = kk0 & 31;
                const int gky = min(max(y + r - 7, 0), WDIM - 1);
                const int gkx0 = min(max(x0 - 7 + c, 0), WDIM - 1);
                const int gkx1 = min(max(x0 - 7 + c + 1, 0), WDIM - 1);
                const short* v0 = (const short*)vs + (qb + (size_t)gky * WDIM + gkx0) * HD + h16;
                const short* v1 = (const short*)vs + (qb + (size_t)gky * WDIM + gkx1) * HD + h16;
                const short8 a0 = *(const short8*)v0, b0 = *(const short8*)v1;
                const short8 a1 = *(const short8*)(v0 + 8), b1 = *(const short8*)(v1 + 8);
                #pragma unroll
                for (int dd = 0; dd < 8; ++dd) dstw[dd * 244 + p] = pk2(a0[dd], b0[dd]);
                #pragma unroll
                for (int dd = 0; dd < 8; ++dd) dstw[(dd + 8) * 244 + p] = pk2(a1[dd], b1[dd]);
            }
        }
        __syncthreads();
        floatx4 acc = {0.f, 0.f, 0.f, 0.f};
        for (int u = wave; u < 15; u += 4) {
            const short8 Af = *(const short8*)(sP + m * 488 + u * 32 + quad * 8);
            const short8 Bf = *(const short8*)(sB + m * 488 + u * 32 + quad * 8);
            acc = __builtin_amdgcn_mfma_f32_16x16x32_bf16(Af, Bf, acc, 0, 0, 0);
        }
        __syncthreads();
        {   // stage Rv^T rows [d-half][w], stride 264 shorts, zeros for w>=225
            unsigned* dstw = (unsigned*)sB;
            for (int p = tid; p < 132; p += 256) {
                const int w0 = 2 * p;
                short8 a0 = {0,0,0,0,0,0,0,0}, a1 = a0, b0 = a0, b1 = a0;
                if (w0 < WS2) {
                    const short* rp = (const short*)relvT + ((size_t)h * WS2 + w0) * HD + h16;
                    a0 = *(const short8*)rp; a1 = *(const short8*)(rp + 8);
                }
                if (w0 + 1 < WS2) {
                    const short* rp = (const short*)relvT + ((size_t)h * WS2 + w0 + 1) * HD + h16;
                    b0 = *(const short8*)rp; b1 = *(const short8*)(rp + 8);
                }
                #pragma unroll
                for (int dd = 0; dd < 8; ++dd) dstw[dd * 132 + p] = pk2(a0[dd], b0[dd]);
                #pragma unroll
                for (int dd = 0; dd < 8; ++dd) dstw[(dd + 8) * 132 + p] = pk2(a1[dd], b1[dd]);
            }
        }
        __syncthreads();
        for (int u = wave; u < 8; u += 4) {
            const short8 Af = *(const short8*)(sPw + m * 264 + u * 32 + quad * 8);
            const short8 Bf = *(const short8*)(sB + m * 264 + u * 32 + quad * 8);
            acc = __builtin_amdgcn_mfma_f32_16x16x32_bf16(Af, Bf, acc, 0, 0, 0);
        }
        __syncthreads();
        #pragma unroll
        for (int rg = 0; rg < 4; ++rg)
            sOh[wave * 256 + (quad * 4 + rg) * 16 + m] = acc[rg];
        __syncthreads();
        {
            const int qq = tid >> 4, dd = tid & 15;
            const float s = sOh[tid] + sOh[256 + tid] + sOh[512 + tid] + sOh[768 + tid];
            if (qq >= wlo) {
                const size_t i = (size_t)y * WDIM + x0 + qq;
                agg[(i * NB + n) * CDIM + h * HD + h16 + dd] = __float2bfloat16(s);
            }
        }
    }
}

// ---------------- Kernel 4: output projection via MFMA (2 o-tiles/wave) ----------
__global__ __launch_bounds__(256) void out_mfma(
    const __hip_bfloat16* __restrict__ agg, const void* __restrict__ Wp,
    const void* __restrict__ bp, const int* __restrict__ flag,
    void* __restrict__ dout)
{
    const bool f32 = (*flag != 0);
    const int wave = threadIdx.x >> 6, lane = threadIdx.x & 63;
    const int t2 = blockIdx.x * 4 + wave;            // 1600 = 200 rb-groups x 8 o-pairs
    const int rb0 = (t2 >> 3) << 4;
    const int o0 = (t2 & 7) << 5;                    // pair covers o0..o0+31
    const int m = lane & 15, qd = lane >> 4;

    const __hip_bfloat16* arow = agg + (size_t)(rb0 + m) * CDIM + qd * 8;

    floatx4 acc0 = {0.f, 0.f, 0.f, 0.f}, acc1 = {0.f, 0.f, 0.f, 0.f};
    #pragma unroll
    for (int k = 0; k < 8; ++k) {
        short8 a  = *(const short8*)(arow + k * 32);
        short8 b0 = ld8bf(Wp, (size_t)(o0 + m) * CDIM + k * 32 + qd * 8, f32);
        short8 b1 = ld8bf(Wp, (size_t)(o0 + 16 + m) * CDIM + k * 32 + qd * 8, f32);
        acc0 = __builtin_amdgcn_mfma_f32_16x16x32_bf16(a, b0, acc0, 0, 0, 0);
        acc1 = __builtin_amdgcn_mfma_f32_16x16x32_bf16(a, b1, acc1, 0, 0, 0);
    }
    const int oa = o0 + (lane & 15), ob = oa + 16;
    const float ba_ = ldf(bp, (size_t)oa, f32);
    const float bb_ = ldf(bp, (size_t)ob, f32);
    #pragma unroll
    for (int rg = 0; rg < 4; ++rg) {
        const int rb = rb0 + (lane >> 4) * 4 + rg;
        st_out(dout, (size_t)rb * CDIM + oa, acc0[rg] + ba_, f32);
        st_out(dout, (size_t)rb * CDIM + ob, acc1[rg] + bb_, f32);
    }
}

extern "C" void kernel_launch(void* const* d_in, const int* in_sizes, int n_in,
                              void* d_out, int out_size, void* d_ws, size_t ws_size,
                              hipStream_t stream)
{
    const void* q   = d_in[0];
    const void* k   = d_in[1];
    const void* v   = d_in[2];
    const void* Wq  = d_in[3];
    const void* bq  = d_in[4];
    const void* Wk  = d_in[5];
    const void* bk  = d_in[6];
    const void* Wv  = d_in[7];
    const void* bv  = d_in[8];
    const void* rkw = d_in[9];
    const void* rkb = d_in[10];
    const void* rlv = d_in[11];
    const void* Wp  = d_in[12];
    const void* bp  = d_in[13];

    // ws layout (6.67 MB): flag(64B) | relvT(115200B) | qs | ks | vs | agg (PROJ bf16 each)
    char* wsb = (char*)d_ws;
    int* flag = (int*)wsb;
    __hip_bfloat16* relvT = (__hip_bfloat16*)(wsb + 64);
    __hip_bfloat16* qs    = (__hip_bfloat16*)(wsb + 64 + 115200);
    __hip_bfloat16* ks    = qs + PROJ;
    __hip_bfloat16* vs    = ks + PROJ;
    __hip_bfloat16* agg   = vs + PROJ;

    prep_kernel<<<8, 256, 0, stream>>>(q, rlv, flag, relvT);
    proj_fused<<<dim3(50, 2, 3), 256, 0, stream>>>(q, k, v, Wq, bq, Wk, bk, Wv, bv,
                                                   flag, qs, ks, vs);
    attn_mfma<<<dim3(120, 16), 256, 0, stream>>>(qs, ks, vs, rkw, rkb, relvT, flag, agg, d_out);
    out_mfma<<<400, 256, 0, stream>>>(agg, Wp, bp, flag, d_out);
}